// Round 13
// baseline (1729.824 us; speedup 1.0000x reference)
//
#include <hip/hip_runtime.h>
#include <hip/hip_fp16.h>
#include <math.h>

#define NN 4003              // label nodes
#define UU 2048              // unify nodes
#define KP 4032              // node dim padded to multiple of 64
#define N4P 4004             // NN rounded up to multiple of 4 (plane width)
#define NORMC (-8.7079796f)  // -log(4003+2048)

using bf16x8 = __attribute__((ext_vector_type(8))) short;
using f32x4  = __attribute__((ext_vector_type(4))) float;

// async global->LDS, 16B per lane; dest is wave-uniform base + lane*16
#define GLL16(g, l) __builtin_amdgcn_global_load_lds( \
    (const __attribute__((address_space(1))) unsigned*)(g), \
    (__attribute__((address_space(3))) unsigned*)(l), 16, 0, 0)

__device__ __forceinline__ ushort f2bf(float x) {
    unsigned u = __builtin_bit_cast(unsigned, x);
    u += 0x7fff + ((u >> 16) & 1);
    return (ushort)(u >> 16);
}
__device__ __forceinline__ float bf2f(ushort h) {
    unsigned u = ((unsigned)h) << 16;
    return __builtin_bit_cast(float, u);
}
__device__ __forceinline__ void bfsplit(float x, ushort& hi, ushort& lo) {
    hi = f2bf(x);
    lo = f2bf(x - bf2f(hi));
}
__device__ __forceinline__ float h2f(ushort h) {
    return __half2float(__ushort_as_half(h));
}

// ---------- concat + bf16 hi/lo split; tail blocks zero v, u_ext pad, counters ----------
__global__ void concat_bf(const float* __restrict__ a, const float* __restrict__ b,
                          ushort* __restrict__ fh, ushort* __restrict__ fl,
                          float* __restrict__ u_ext, float* __restrict__ v,
                          int* __restrict__ ctr) {
    int bid = blockIdx.x;
    if (bid >= 1001) {
        if (bid < 1003) {                       // zero v: 512 float4
            int t = (bid - 1001) * 256 + threadIdx.x;
            if (t < 512) ((float4*)v)[t] = (float4){0.f, 0.f, 0.f, 0.f};
        } else if (bid == 1003) {               // u_ext pad
            if ((int)threadIdx.x < KP - NN) u_ext[NN + threadIdx.x] = -1e30f;
        } else {                                // zero split-K counters: 15*256 ints
            int t = (bid - 1004) * 256 + threadIdx.x;   // 4 blocks, int4 each
            if (t < 960) ((int4*)ctr)[t] = (int4){0, 0, 0, 0};
        }
        return;
    }
    int i = bid * 256 + threadIdx.x;
    const int tot4 = NN * 256 / 4;
    if (i >= tot4) return;
    float4 vv = (i < 256000) ? ((const float4*)a)[i] : ((const float4*)b)[i - 256000];
    ushort4 hv, lv;
    bfsplit(vv.x, hv.x, lv.x); bfsplit(vv.y, hv.y, lv.y);
    bfsplit(vv.z, hv.z, lv.z); bfsplit(vv.w, hv.w, lv.w);
    *(ushort4*)(fh + ((size_t)i << 2)) = hv;
    *(ushort4*)(fl + ((size_t)i << 2)) = lv;
}

// ---------- batched weight convert: 6 weights, blockIdx.z selects ----------
__global__ void convW_all(
        const float* __restrict__ Wa, const float* __restrict__ Wb_,
        const float* __restrict__ Wc, const float* __restrict__ Wd,
        const float* __restrict__ We, const float* __restrict__ Wf,
        ushort* T0h, ushort* T0l, ushort* T1h, ushort* T1l,
        ushort* T2h, ushort* T2l, ushort* T3h, ushort* T3l,
        ushort* T4h, ushort* T4l, ushort* T5h, ushort* T5l) {
    __shared__ float tile[32][33];
    const float* W; ushort* Th; ushort* Tl; int K, Nw;
    switch (blockIdx.z) {
        case 0:  W = Wa;  Th = T0h; Tl = T0l; K = 256; Nw = 256; break;
        case 1:  W = Wb_; Th = T1h; Tl = T1l; K = 256; Nw = 256; break;
        case 2:  W = Wc;  Th = T2h; Tl = T2l; K = 256; Nw = 256; break;
        case 3:  W = Wd;  Th = T3h; Tl = T3l; K = 256; Nw = 256; break;
        case 4:  W = We;  Th = T4h; Tl = T4l; K = 256; Nw = 512; break;
        default: W = Wf;  Th = T5h; Tl = T5l; K = 512; Nw = 256; break;
    }
    int bx = blockIdx.x, by = blockIdx.y;
    if (bx * 32 >= Nw || by * 32 >= K) return;
    int tx = threadIdx.x;
    for (int r = threadIdx.y; r < 32; r += 8)
        tile[r][tx] = W[(size_t)(by * 32 + r) * Nw + bx * 32 + tx];
    __syncthreads();
    for (int r = threadIdx.y; r < 32; r += 8) {
        int n = bx * 32 + r, k = by * 32 + tx;
        ushort hi, lo; bfsplit(tile[tx][r], hi, lo);
        Th[(size_t)n * K + k] = hi;
        Tl[(size_t)n * K + k] = lo;
    }
}

// ---------- S f32 -> Shm fp16 [NN][UU] AND STh fp16 [UU][KP], one read of S ----------
__global__ void conv_both(const float* __restrict__ in, ushort* __restrict__ Sh,
                          ushort* __restrict__ STh) {
    __shared__ float tile[32][33];
    int x = blockIdx.x * 32 + threadIdx.x;       // UU dim
    int y0 = blockIdx.y * 32;                    // NN dim
    for (int r = threadIdx.y; r < 32; r += 8) {
        int y = y0 + r;
        float vv = (y < NN) ? in[(size_t)y * UU + x] : 0.0f;
        tile[r][threadIdx.x] = vv;
        if (y < NN)
            Sh[(size_t)y * UU + x] = __half_as_ushort(__float2half(vv));
    }
    __syncthreads();
    int oc = y0 + threadIdx.x;
    for (int r = threadIdx.y; r < 32; r += 8) {
        int orow = blockIdx.x * 32 + r;
        STh[(size_t)orow * KP + oc] = __half_as_ushort(__float2half(tile[threadIdx.x][r]));
    }
}

__device__ __forceinline__ void wave_lse_reduce(float& m, float& s) {
    #pragma unroll
    for (int off = 1; off < 64; off <<= 1) {
        float om = __shfl_xor(m, off, 64), os = __shfl_xor(s, off, 64);
        float nm = fmaxf(m, om);
        s = s * __expf(m - nm) + os * __expf(om - nm);
        m = nm;
    }
}

// ------- quad-row fp16 logsumexp: outv[r] = NORMC - lse_j(Sh[r][j] + addv[j]) -------
__global__ __launch_bounds__(256) void lse4h(const ushort* __restrict__ Sh, int lda,
                                             const float* __restrict__ addv,
                                             float* __restrict__ outv, int C, int R) {
    int r0 = blockIdx.x * 4;
    const ushort* rp[4];
    #pragma unroll
    for (int q = 0; q < 4; ++q) {
        int r = r0 + q; if (r >= R) r = R - 1;
        rp[q] = Sh + (size_t)r * lda;
    }
    float m[4], s[4];
    #pragma unroll
    for (int q = 0; q < 4; ++q) { m[q] = -INFINITY; s[q] = 0.0f; }
    int C4 = C >> 2;
    for (int j = threadIdx.x; j < C4; j += 256) {
        float4 av = ((const float4*)addv)[j];
        #pragma unroll
        for (int q = 0; q < 4; ++q) {
            ushort4 pa = *(const ushort4*)(rp[q] + (j << 2));
            float x0 = h2f(pa.x) + av.x, x1 = h2f(pa.y) + av.y;
            float x2 = h2f(pa.z) + av.z, x3 = h2f(pa.w) + av.w;
            float mx = fmaxf(fmaxf(x0, x1), fmaxf(x2, x3));
            float nm = fmaxf(m[q], mx);
            s[q] = s[q] * __expf(m[q] - nm) + __expf(x0 - nm) + __expf(x1 - nm)
                                            + __expf(x2 - nm) + __expf(x3 - nm);
            m[q] = nm;
        }
    }
    int rem = C & 3;
    if ((int)threadIdx.x < rem) {
        int j = (C4 << 2) + threadIdx.x;
        float av = addv[j];
        #pragma unroll
        for (int q = 0; q < 4; ++q) {
            float x = h2f(rp[q][j]) + av;
            float nm = fmaxf(m[q], x);
            s[q] = s[q] * __expf(m[q] - nm) + __expf(x - nm);
            m[q] = nm;
        }
    }
    #pragma unroll
    for (int q = 0; q < 4; ++q) wave_lse_reduce(m[q], s[q]);
    __shared__ float sm[4][4], ss[4][4];   // [wave][q]
    int w = threadIdx.x >> 6;
    if ((threadIdx.x & 63) == 0) {
        #pragma unroll
        for (int q = 0; q < 4; ++q) { sm[w][q] = m[q]; ss[w][q] = s[q]; }
    }
    __syncthreads();
    if (threadIdx.x < 4) {
        int q = threadIdx.x;
        float mm = sm[0][q], sa = ss[0][q];
        #pragma unroll
        for (int i = 1; i < 4; ++i) {
            float om = sm[i][q], os = ss[i][q];
            float nm = fmaxf(mm, om);
            sa = sa * __expf(mm - nm) + os * __expf(om - nm);
            mm = nm;
        }
        int r = r0 + q;
        if (r < R) outv[r] = NORMC - (mm + __logf(sa));
    }
}

// ---------- on-the-fly exp from fp16 S: 8 elems -> bf16 hi/lo packed ----------
__device__ __forceinline__ void exp_row8h(const ushort* __restrict__ Sh,
        const float* __restrict__ rowadd, const float* __restrict__ coladd,
        int lda, int M, int gm, int kbase, uint4& hiv, uint4& lov) {
    ushort h[8], l[8];
    if (gm < M) {
        float ra = rowadd[gm] - NORMC;
        const ushort* rp = Sh + (size_t)gm * lda + kbase;
        ushort4 q0 = *(const ushort4*)rp;
        ushort4 q1 = *(const ushort4*)(rp + 4);
        float4 ca = *(const float4*)(coladd + kbase);
        float4 cb = *(const float4*)(coladd + kbase + 4);
        float vv[8] = {h2f(q0.x) + ca.x, h2f(q0.y) + ca.y, h2f(q0.z) + ca.z, h2f(q0.w) + ca.w,
                       h2f(q1.x) + cb.x, h2f(q1.y) + cb.y, h2f(q1.z) + cb.z, h2f(q1.w) + cb.w};
        #pragma unroll
        for (int e = 0; e < 8; ++e) {
            float av = __expf(vv[e] + ra);
            bfsplit(av, h[e], l[e]);
        }
    } else {
        #pragma unroll
        for (int e = 0; e < 8; ++e) { h[e] = 0; l[e] = 0; }
    }
    hiv.x = (unsigned)h[0] | ((unsigned)h[1] << 16);
    hiv.y = (unsigned)h[2] | ((unsigned)h[3] << 16);
    hiv.z = (unsigned)h[4] | ((unsigned)h[5] << 16);
    hiv.w = (unsigned)h[6] | ((unsigned)h[7] << 16);
    lov.x = (unsigned)l[0] | ((unsigned)l[1] << 16);
    lov.y = (unsigned)l[2] | ((unsigned)l[3] << 16);
    lov.z = (unsigned)l[4] | ((unsigned)l[5] << 16);
    lov.w = (unsigned)l[6] | ((unsigned)l[7] << 16);
}

// ============ BIG GEMM: 64x256 tile, 8 waves, split-K + fused semaphore reduction ====
// Last-arriving z-block for each row-tile re-reads planes in z-ascending order
// (bitwise identical to the old reduce_ks) and applies the epilogue.
template<int ACT, int BIAS, int RES>
__global__ __launch_bounds__(512) __attribute__((amdgpu_waves_per_eu(2, 4)))
void gemm_bigN(
        const ushort* __restrict__ Sh, const float* __restrict__ rowadd,
        const float* __restrict__ coladd, int lda,
        const ushort* __restrict__ Bh, const ushort* __restrict__ Bl, int ldb,
        float* __restrict__ P, int M, int K, int Kc,
        const float* __restrict__ bias,
        const ushort* __restrict__ Rh, const ushort* __restrict__ Rl,
        ushort* __restrict__ Ch, ushort* __restrict__ Cl,
        int* __restrict__ ctr) {
    __shared__ __align__(16) ushort SM[2 * 64 * 64 + 2 * 256 * 64];   // 80 KB
    ushort* As0 = SM;
    ushort* As1 = SM + 4096;
    ushort* Bs0 = SM + 8192;
    ushort* Bs1 = SM + 8192 + 16384;
    const int tid = threadIdx.x;
    const int bm = blockIdx.x << 6;
    const int lane = tid & 63;
    const int wv = tid >> 6;
    const int wr = (wv >> 2) << 5;
    const int wc = (wv & 3) << 6;
    const int kb = blockIdx.y * Kc;
    int ke = kb + Kc; if (ke > K) ke = K;
    const int arow = tid >> 3, ak8 = (tid & 7) << 3;
    const int as = ((arow << 6) + ak8) ^ ((arow & 7) << 3);
    const int brow_base = wv << 5;
    f32x4 acc[2][4] = {};
    for (int k0 = kb; k0 < ke; k0 += 64) {
        uint4 ah, al;
        exp_row8h(Sh, rowadd, coladd, lda, M, bm + arow, k0 + ak8, ah, al);
        __syncthreads();
        #pragma unroll
        for (int t = 0; t < 4; ++t) {
            int rb2 = brow_base + (t << 3);
            int row = rb2 + (lane >> 3);
            int kksrc = (((lane & 7) ^ (row & 7)) << 3);
            size_t go = (size_t)row * ldb + k0 + kksrc;
            GLL16(Bh + go, &Bs0[rb2 << 6]);
            GLL16(Bl + go, &Bs1[rb2 << 6]);
        }
        *(uint4*)&As0[as] = ah;
        *(uint4*)&As1[as] = al;
        __syncthreads();
        #pragma unroll
        for (int ks = 0; ks < 2; ++ks) {
            int kq = (ks << 5) + ((lane >> 4) << 3);
            bf16x8 fah[2], fal[2], fbh[4], fbl[4];
            #pragma unroll
            for (int f = 0; f < 2; ++f) {
                int rr = wr + (f << 4) + (lane & 15);
                int ia = ((rr << 6) + kq) ^ ((rr & 7) << 3);
                fah[f] = *(const bf16x8*)&As0[ia];
                fal[f] = *(const bf16x8*)&As1[ia];
            }
            #pragma unroll
            for (int g = 0; g < 4; ++g) {
                int cc = wc + (g << 4) + (lane & 15);
                int ib = ((cc << 6) + kq) ^ ((cc & 7) << 3);
                fbh[g] = *(const bf16x8*)&Bs0[ib];
                fbl[g] = *(const bf16x8*)&Bs1[ib];
            }
            #pragma unroll
            for (int i = 0; i < 2; ++i)
                #pragma unroll
                for (int j = 0; j < 4; ++j) {
                    acc[i][j] = __builtin_amdgcn_mfma_f32_16x16x32_bf16(fah[i], fbh[j], acc[i][j], 0, 0, 0);
                    acc[i][j] = __builtin_amdgcn_mfma_f32_16x16x32_bf16(fah[i], fbl[j], acc[i][j], 0, 0, 0);
                    acc[i][j] = __builtin_amdgcn_mfma_f32_16x16x32_bf16(fal[i], fbh[j], acc[i][j], 0, 0, 0);
                }
        }
    }
    // ---- LDS-staged coalesced plane write ----
    __syncthreads();
    float* LF = (float*)SM;               // [64][256] f32
    #pragma unroll
    for (int i = 0; i < 2; ++i) {
        int row0 = wr + (i << 4) + ((lane >> 4) << 2);
        #pragma unroll
        for (int j = 0; j < 4; ++j) {
            int col = wc + (j << 4) + (lane & 15);
            #pragma unroll
            for (int r = 0; r < 4; ++r)
                LF[(row0 + r) * 256 + col] = acc[i][j][r];
        }
    }
    __syncthreads();
    float* Pp = P + (size_t)blockIdx.y * ((size_t)M * 256);
    #pragma unroll
    for (int it = 0; it < 8; ++it) {
        int idx = tid + (it << 9);
        int row = idx >> 6, c4 = (idx & 63) << 2;
        if (bm + row < M)
            *(float4*)(Pp + (size_t)(bm + row) * 256 + c4) = *(const float4*)&LF[row * 256 + c4];
    }
    // ---- semaphore: last z-block for this row-tile reduces ----
    __threadfence();
    __shared__ int lastf;
    if (tid == 0) lastf = (atomicAdd(ctr + blockIdx.x, 1) == (int)gridDim.y - 1);
    __syncthreads();
    if (!lastf) return;
    __threadfence();
    const int zg = gridDim.y;
    const size_t pstr = (size_t)M * 256;
    #pragma unroll
    for (int it = 0; it < 8; ++it) {
        int idx = tid + (it << 9);
        int row = idx >> 6, c4 = (idx & 63) << 2;
        int grow = bm + row;
        if (grow >= M) continue;
        const float* base = P + (size_t)grow * 256 + c4;
        float4 a = *(const float4*)base;
        for (int z = 1; z < zg; ++z) {
            float4 b2 = *(const float4*)(base + (size_t)z * pstr);
            a.x += b2.x; a.y += b2.y; a.z += b2.z; a.w += b2.w;
        }
        if (BIAS == 1) {
            float4 bv = *(const float4*)(bias + c4);
            a.x += bv.x; a.y += bv.y; a.z += bv.z; a.w += bv.w;
        }
        if (RES) {
            size_t ro = (size_t)grow * 256 + c4;
            ushort4 rh = *(const ushort4*)(Rh + ro);
            ushort4 rl = *(const ushort4*)(Rl + ro);
            a.x += bf2f(rh.x) + bf2f(rl.x); a.y += bf2f(rh.y) + bf2f(rl.y);
            a.z += bf2f(rh.z) + bf2f(rl.z); a.w += bf2f(rh.w) + bf2f(rl.w);
        }
        if (ACT == 2) {
            a.x = tanhf(a.x); a.y = tanhf(a.y); a.z = tanhf(a.z); a.w = tanhf(a.w);
        }
        ushort4 hv, lv;
        bfsplit(a.x, hv.x, lv.x); bfsplit(a.y, hv.y, lv.y);
        bfsplit(a.z, hv.z, lv.z); bfsplit(a.w, hv.w, lv.w);
        size_t co = (size_t)grow * 256 + c4;
        *(ushort4*)(Ch + co) = hv;
        *(ushort4*)(Cl + co) = lv;
    }
}

// ============ small GEMM (64x64 tile), split-K + fused semaphore reduction ============
// BIAS: 0 none, 1 per-col, 2 per-row. OUTF: 1 -> f32 Cf, else bf16 pair Ch/Cl.
template<int ACT, int BIAS, int OUTF>
__global__ __launch_bounds__(256) __attribute__((amdgpu_waves_per_eu(4, 8)))
void gemm_ks(
        const ushort* __restrict__ Ah, const ushort* __restrict__ Al, int lda,
        const ushort* __restrict__ Bh, const ushort* __restrict__ Bl, int ldb, int Nb,
        float* __restrict__ P, int M, int Nplane, int K, int Kc,
        const float* __restrict__ bias,
        float* __restrict__ Cf, ushort* __restrict__ Ch, ushort* __restrict__ Cl,
        int ldo, int* __restrict__ ctr) {
    __shared__ __align__(16) ushort SM[4 * 64 * 64];   // 32 KB
    ushort* As0 = SM;
    ushort* As1 = SM + 4096;
    ushort* Bs0 = SM + 8192;
    ushort* Bs1 = SM + 12288;
    const int tid = threadIdx.x;
    const int bm = blockIdx.y << 6, bn = blockIdx.x << 6;
    const int lane = tid & 63;
    const int wv = tid >> 6;
    const int wm = (wv >> 1) << 5, wn = (wv & 1) << 5;
    const int kb = blockIdx.z * Kc;
    int ke = kb + Kc; if (ke > K) ke = K;
    const int rb = wv << 4;
    f32x4 acc[2][2] = {};
    for (int k0 = kb; k0 < ke; k0 += 64) {
        __syncthreads();
        #pragma unroll
        for (int t = 0; t < 2; ++t) {
            int rb2 = rb + (t << 3);
            int row = rb2 + (lane >> 3);
            int kksrc = (((lane & 7) ^ (row & 7)) << 3);
            int ga = bm + row; ga = (ga < M) ? ga : (M - 1);
            int gb = bn + row; gb = (gb < Nb) ? gb : (Nb - 1);
            size_t goa = (size_t)ga * lda + k0 + kksrc;
            size_t gob = (size_t)gb * ldb + k0 + kksrc;
            GLL16(Ah + goa, &As0[rb2 << 6]);
            GLL16(Al + goa, &As1[rb2 << 6]);
            GLL16(Bh + gob, &Bs0[rb2 << 6]);
            GLL16(Bl + gob, &Bs1[rb2 << 6]);
        }
        __syncthreads();
        #pragma unroll
        for (int ks = 0; ks < 2; ++ks) {
            int kbq = (ks << 5) + ((lane >> 4) << 3);
            bf16x8 fah[2], fal[2], fbh[2], fbl[2];
            #pragma unroll
            for (int f = 0; f < 2; ++f) {
                int rr = wm + (f << 4) + (lane & 15);
                int ia = ((rr << 6) + kbq) ^ ((rr & 7) << 3);
                fah[f] = *(const bf16x8*)&As0[ia];
                fal[f] = *(const bf16x8*)&As1[ia];
                int cc = wn + (f << 4) + (lane & 15);
                int ib = ((cc << 6) + kbq) ^ ((cc & 7) << 3);
                fbh[f] = *(const bf16x8*)&Bs0[ib];
                fbl[f] = *(const bf16x8*)&Bs1[ib];
            }
            #pragma unroll
            for (int i = 0; i < 2; ++i)
                #pragma unroll
                for (int j = 0; j < 2; ++j) {
                    acc[i][j] = __builtin_amdgcn_mfma_f32_16x16x32_bf16(fah[i], fbh[j], acc[i][j], 0, 0, 0);
                    acc[i][j] = __builtin_amdgcn_mfma_f32_16x16x32_bf16(fah[i], fbl[j], acc[i][j], 0, 0, 0);
                    acc[i][j] = __builtin_amdgcn_mfma_f32_16x16x32_bf16(fal[i], fbh[j], acc[i][j], 0, 0, 0);
                }
        }
    }
    // ---- LDS-staged coalesced plane write ----
    __syncthreads();
    float* LF = (float*)SM;               // [64][64] f32
    #pragma unroll
    for (int i = 0; i < 2; ++i) {
        int row0 = wm + (i << 4) + ((lane >> 4) << 2);
        #pragma unroll
        for (int j = 0; j < 2; ++j) {
            int col = wn + (j << 4) + (lane & 15);
            #pragma unroll
            for (int r = 0; r < 4; ++r)
                LF[(row0 + r) * 64 + col] = acc[i][j][r];
        }
    }
    __syncthreads();
    float* Pp = P + (size_t)blockIdx.z * ((size_t)M * Nplane);
    #pragma unroll
    for (int it = 0; it < 4; ++it) {
        int idx = tid + (it << 8);
        int row = idx >> 4, c4 = (idx & 15) << 2;
        if (bm + row < M && bn + c4 < Nplane)
            *(float4*)(Pp + (size_t)(bm + row) * Nplane + bn + c4) = *(const float4*)&LF[row * 64 + c4];
    }
    // ---- semaphore: last z-block for this tile reduces ----
    __threadfence();
    __shared__ int lastf;
    if (tid == 0)
        lastf = (atomicAdd(ctr + blockIdx.y * gridDim.x + blockIdx.x, 1) == (int)gridDim.z - 1);
    __syncthreads();
    if (!lastf) return;
    __threadfence();
    const int zg = gridDim.z;
    const size_t pstr = (size_t)M * Nplane;
    #pragma unroll
    for (int it = 0; it < 16; ++it) {
        int idx = tid + (it << 8);
        int row = idx >> 4, c4 = (idx & 15) << 2;
        int grow = bm + row, gcol = bn + c4;
        if (grow >= M || gcol >= Nplane) continue;
        const float* base = P + (size_t)grow * Nplane + gcol;
        float4 a = *(const float4*)base;
        for (int z = 1; z < zg; ++z) {
            float4 b2 = *(const float4*)(base + (size_t)z * pstr);
            a.x += b2.x; a.y += b2.y; a.z += b2.z; a.w += b2.w;
        }
        if (BIAS == 1) {
            float4 bv = *(const float4*)(bias + gcol);
            a.x += bv.x; a.y += bv.y; a.z += bv.z; a.w += bv.w;
        }
        if (BIAS == 2) {
            float sb = bias[grow];
            a.x += sb; a.y += sb; a.z += sb; a.w += sb;
        }
        if (ACT == 1) {
            a.x = fmaxf(a.x, 0.f); a.y = fmaxf(a.y, 0.f);
            a.z = fmaxf(a.z, 0.f); a.w = fmaxf(a.w, 0.f);
        }
        size_t co = (size_t)grow * ldo + gcol;
        if (OUTF) {
            *(float4*)(Cf + co) = a;
        } else {
            ushort4 hv, lv;
            bfsplit(a.x, hv.x, lv.x); bfsplit(a.y, hv.y, lv.y);
            bfsplit(a.z, hv.z, lv.z); bfsplit(a.w, hv.w, lv.w);
            *(ushort4*)(Ch + co) = hv;
            *(ushort4*)(Cl + co) = lv;
        }
    }
}

extern "C" void kernel_launch(void* const* d_in, const int* in_sizes, int n_in,
                              void* d_out, int out_size, void* d_ws, size_t ws_size,
                              hipStream_t stream) {
    const float* dsf = (const float*)d_in[0];
    const float* unl = (const float*)d_in[1];
    const float* S   = (const float*)d_in[2];
    const float* Wb  = (const float*)d_in[3];
    const float* bb  = (const float*)d_in[4];
    const float* gcW[3] = {(const float*)d_in[5], (const float*)d_in[7], (const float*)d_in[9]};
    const float* gcb[3] = {(const float*)d_in[6], (const float*)d_in[8], (const float*)d_in[10]};
    const float* W1 = (const float*)d_in[11];
    const float* b1 = (const float*)d_in[12];
    const float* W2 = (const float*)d_in[13];
    const float* b2 = (const float*)d_in[14];
    float* out = (float*)d_out;

    // -------- workspace carve --------
    char* p = (char*)d_ws;
    ushort* Shm = (ushort*)p; p += (size_t)NN * UU * 2;                // 16.4 MB fp16 S
    ushort* STh = (ushort*)p; p += (size_t)UU * KP * 2;                // 16.5 MB fp16 S^T
    float* P    = (float*)p;  p += (size_t)8 * NN * 256 * 4;           // 32.8 MB planes
    ushort* fh = (ushort*)p; ushort* fl = fh + (size_t)NN * 256; p += (size_t)NN * 256 * 4;
    ushort* xh = (ushort*)p; ushort* xl = xh + (size_t)NN * 256; p += (size_t)NN * 256 * 4;
    ushort* xTh = (ushort*)p; ushort* xTl = xTh + (size_t)256 * KP; p += (size_t)256 * KP * 4;
    ushort* huh = (ushort*)p; ushort* hul = huh + (size_t)UU * 256; p += (size_t)UU * 256 * 4;
    ushort* tuTh = (ushort*)p; ushort* tuTl = tuTh + (size_t)256 * UU; p += (size_t)256 * UU * 4;
    ushort* tnTh = (ushort*)p; ushort* tnTl = tnTh + (size_t)256 * KP; p += (size_t)256 * KP * 4;
    float* u_ext = (float*)p; p += KP * 4;
    float* v     = (float*)p; p += UU * 4;
    ushort* WbTh = (ushort*)p; ushort* WbTl = WbTh + 256 * 256; p += 256 * 256 * 4;
    ushort* gWh[3]; ushort* gWl[3];
    for (int l = 0; l < 3; ++l) { gWh[l] = (ushort*)p; gWl[l] = gWh[l] + 256 * 256; p += 256 * 256 * 4; }
    ushort* W1Th = (ushort*)p; ushort* W1Tl = W1Th + 512 * 256; p += 512 * 256 * 4;
    ushort* W2Th = (ushort*)p; ushort* W2Tl = W2Th + 256 * 512; p += 256 * 512 * 4;
    int* CTR = (int*)p; p += 15 * 256 * 4;     // split-K semaphores (zeroed each call)
    // h1 pair aliases x + start of xT region (both dead by head time)
    ushort* h1h = xh; ushort* h1l = h1h + (size_t)UU * 512;
    (void)ws_size;
    int ci = 0;   // counter-array cursor

    // -------- prep --------
    concat_bf<<<dim3(1008), dim3(256), 0, stream>>>(dsf, unl, fh, fl, u_ext, v, CTR);
    convW_all<<<dim3(16, 16, 6), dim3(32, 8), 0, stream>>>(
        Wb, gcW[0], gcW[1], gcW[2], W1, W2,
        WbTh, WbTl, gWh[0], gWl[0], gWh[1], gWl[1], gWh[2], gWl[2],
        W1Th, W1Tl, W2Th, W2Tl);
    conv_both<<<dim3(64, 126), dim3(32, 8), 0, stream>>>(S, Shm, STh);

    // x = relu(feats @ Wb + bb)  [NN][256]
    gemm_ks<1,1,0><<<dim3(4, 63, 2), 256, 0, stream>>>(
        fh, fl, 256, WbTh, WbTl, 256, 256, P, NN, 256, 256, 128,
        bb, nullptr, xh, xl, 256, CTR + 256 * ci); ci++;
    // xT = x^T  [256][KP] (per-row bias)
    gemm_ks<1,2,0><<<dim3(63, 4, 2), 256, 0, stream>>>(
        WbTh, WbTl, 256, fh, fl, 256, NN, P, 256, N4P, 256, 128,
        bb, nullptr, xTh, xTl, KP, CTR + 256 * ci); ci++;

    // -------- Sinkhorn (fp16 S, f32 math): 40 small launches --------
    // (R10 lesson: grid.sync() ~25 us/sync on MI355X — cooperative fusion is 4x slower.)
    for (int it = 0; it < 20; ++it) {
        lse4h<<<dim3((NN + 3) / 4), dim3(256), 0, stream>>>(Shm, UU, v, u_ext, UU, NN);
        lse4h<<<dim3(UU / 4),       dim3(256), 0, stream>>>(STh, KP, u_ext, v, NN, UU);
    }

    // -------- G1: hu0 = A^T @ x  [UU][256] --------
    gemm_bigN<0,0,0><<<dim3(32, 8), 512, 0, stream>>>(
        STh, v, u_ext, KP, xTh, xTl, KP, P, UU, KP, 512,
        nullptr, nullptr, nullptr, huh, hul, CTR + 256 * ci); ci++;

    // -------- 3 GCN layers --------
    for (int l = 0; l < 3; ++l) {
        const ushort* hnh = (l == 0) ? xh : fh;
        const ushort* hnl = (l == 0) ? xl : fl;
        if (l < 2) {
            gemm_ks<0,0,0><<<dim3(32, 4, 2), 256, 0, stream>>>(
                gWh[l], gWl[l], 256, huh, hul, 256, UU, P, 256, UU, 256, 128,
                nullptr, nullptr, tuTh, tuTl, UU, CTR + 256 * ci); ci++;
        }
        gemm_ks<0,0,0><<<dim3(63, 4, 2), 256, 0, stream>>>(
            gWh[l], gWl[l], 256, hnh, hnl, 256, NN, P, 256, N4P, 256, 128,
            nullptr, nullptr, tnTh, tnTl, KP, CTR + 256 * ci); ci++;
        if (l < 2) {
            // hn_next = tanh(A @ t_u + b + hn), z=6
            gemm_bigN<2,1,1><<<dim3(63, 6), 512, 0, stream>>>(
                Shm, u_ext, v, UU, tuTh, tuTl, UU, P, NN, UU, 384,
                gcb[l], hnh, hnl, fh, fl, CTR + 256 * ci); ci++;
        }
        // hu_next = tanh(A^T @ t_n + b + hu)
        gemm_bigN<2,1,1><<<dim3(32, 8), 512, 0, stream>>>(
            STh, v, u_ext, KP, tnTh, tnTl, KP, P, UU, KP, 512,
            gcb[l], huh, hul, huh, hul, CTR + 256 * ci); ci++;
    }

    // -------- head --------
    gemm_ks<1,1,0><<<dim3(8, 32, 2), 256, 0, stream>>>(
        huh, hul, 256, W1Th, W1Tl, 256, 512, P, UU, 512, 256, 128,
        b1, nullptr, h1h, h1l, 512, CTR + 256 * ci); ci++;
    gemm_ks<0,1,1><<<dim3(4, 32, 4), 256, 0, stream>>>(
        h1h, h1l, 512, W2Th, W2Tl, 512, 256, P, UU, 256, 512, 128,
        b2, out, nullptr, nullptr, 256, CTR + 256 * ci); ci++;
}

// Round 14
// 534.453 us; speedup vs baseline: 3.2366x; 3.2366x over previous
//
#include <hip/hip_runtime.h>
#include <hip/hip_fp16.h>
#include <math.h>

#define NN 4003              // label nodes
#define UU 2048              // unify nodes
#define KP 4032              // node dim padded to multiple of 64
#define N4P 4004             // NN rounded up to multiple of 4 (plane width)
#define NORMC (-8.7079796f)  // -log(4003+2048)

using bf16x8 = __attribute__((ext_vector_type(8))) short;
using f32x4  = __attribute__((ext_vector_type(4))) float;

// async global->LDS, 16B per lane; dest is wave-uniform base + lane*16
#define GLL16(g, l) __builtin_amdgcn_global_load_lds( \
    (const __attribute__((address_space(1))) unsigned*)(g), \
    (__attribute__((address_space(3))) unsigned*)(l), 16, 0, 0)

__device__ __forceinline__ ushort f2bf(float x) {
    unsigned u = __builtin_bit_cast(unsigned, x);
    u += 0x7fff + ((u >> 16) & 1);
    return (ushort)(u >> 16);
}
__device__ __forceinline__ float bf2f(ushort h) {
    unsigned u = ((unsigned)h) << 16;
    return __builtin_bit_cast(float, u);
}
__device__ __forceinline__ void bfsplit(float x, ushort& hi, ushort& lo) {
    hi = f2bf(x);
    lo = f2bf(x - bf2f(hi));
}
__device__ __forceinline__ float h2f(ushort h) {
    return __half2float(__ushort_as_half(h));
}

// ---------- concat + bf16 hi/lo split; tail blocks zero v and init u_ext pad ----------
__global__ void concat_bf(const float* __restrict__ a, const float* __restrict__ b,
                          ushort* __restrict__ fh, ushort* __restrict__ fl,
                          float* __restrict__ u_ext, float* __restrict__ v) {
    int bid = blockIdx.x;
    if (bid >= 1001) {
        if (bid < 1003) {                       // zero v: 512 float4
            int t = (bid - 1001) * 256 + threadIdx.x;
            if (t < 512) ((float4*)v)[t] = (float4){0.f, 0.f, 0.f, 0.f};
        } else {                                // u_ext pad
            if ((int)threadIdx.x < KP - NN) u_ext[NN + threadIdx.x] = -1e30f;
        }
        return;
    }
    int i = bid * 256 + threadIdx.x;
    const int tot4 = NN * 256 / 4;
    if (i >= tot4) return;
    float4 vv = (i < 256000) ? ((const float4*)a)[i] : ((const float4*)b)[i - 256000];
    ushort4 hv, lv;
    bfsplit(vv.x, hv.x, lv.x); bfsplit(vv.y, hv.y, lv.y);
    bfsplit(vv.z, hv.z, lv.z); bfsplit(vv.w, hv.w, lv.w);
    *(ushort4*)(fh + ((size_t)i << 2)) = hv;
    *(ushort4*)(fl + ((size_t)i << 2)) = lv;
}

// ---------- batched weight convert: 6 weights, blockIdx.z selects ----------
__global__ void convW_all(
        const float* __restrict__ Wa, const float* __restrict__ Wb_,
        const float* __restrict__ Wc, const float* __restrict__ Wd,
        const float* __restrict__ We, const float* __restrict__ Wf,
        ushort* T0h, ushort* T0l, ushort* T1h, ushort* T1l,
        ushort* T2h, ushort* T2l, ushort* T3h, ushort* T3l,
        ushort* T4h, ushort* T4l, ushort* T5h, ushort* T5l) {
    __shared__ float tile[32][33];
    const float* W; ushort* Th; ushort* Tl; int K, Nw;
    switch (blockIdx.z) {
        case 0:  W = Wa;  Th = T0h; Tl = T0l; K = 256; Nw = 256; break;
        case 1:  W = Wb_; Th = T1h; Tl = T1l; K = 256; Nw = 256; break;
        case 2:  W = Wc;  Th = T2h; Tl = T2l; K = 256; Nw = 256; break;
        case 3:  W = Wd;  Th = T3h; Tl = T3l; K = 256; Nw = 256; break;
        case 4:  W = We;  Th = T4h; Tl = T4l; K = 256; Nw = 512; break;
        default: W = Wf;  Th = T5h; Tl = T5l; K = 512; Nw = 256; break;
    }
    int bx = blockIdx.x, by = blockIdx.y;
    if (bx * 32 >= Nw || by * 32 >= K) return;
    int tx = threadIdx.x;
    for (int r = threadIdx.y; r < 32; r += 8)
        tile[r][tx] = W[(size_t)(by * 32 + r) * Nw + bx * 32 + tx];
    __syncthreads();
    for (int r = threadIdx.y; r < 32; r += 8) {
        int n = bx * 32 + r, k = by * 32 + tx;
        ushort hi, lo; bfsplit(tile[tx][r], hi, lo);
        Th[(size_t)n * K + k] = hi;
        Tl[(size_t)n * K + k] = lo;
    }
}

// ---------- S f32 -> Shm fp16 [NN][UU] AND STh fp16 [UU][KP], one read of S ----------
__global__ void conv_both(const float* __restrict__ in, ushort* __restrict__ Sh,
                          ushort* __restrict__ STh) {
    __shared__ float tile[32][33];
    int x = blockIdx.x * 32 + threadIdx.x;       // UU dim
    int y0 = blockIdx.y * 32;                    // NN dim
    for (int r = threadIdx.y; r < 32; r += 8) {
        int y = y0 + r;
        float vv = (y < NN) ? in[(size_t)y * UU + x] : 0.0f;
        tile[r][threadIdx.x] = vv;
        if (y < NN)
            Sh[(size_t)y * UU + x] = __half_as_ushort(__float2half(vv));
    }
    __syncthreads();
    int oc = y0 + threadIdx.x;
    for (int r = threadIdx.y; r < 32; r += 8) {
        int orow = blockIdx.x * 32 + r;
        STh[(size_t)orow * KP + oc] = __half_as_ushort(__float2half(tile[threadIdx.x][r]));
    }
}

__device__ __forceinline__ void wave_lse_reduce(float& m, float& s) {
    #pragma unroll
    for (int off = 1; off < 64; off <<= 1) {
        float om = __shfl_xor(m, off, 64), os = __shfl_xor(s, off, 64);
        float nm = fmaxf(m, om);
        s = s * __expf(m - nm) + os * __expf(om - nm);
        m = nm;
    }
}
__device__ __forceinline__ void lse8(uint4 pk, float4 a0, float4 a1, float& m, float& s) {
    float x0 = h2f((ushort)(pk.x & 0xffff)) + a0.x;
    float x1 = h2f((ushort)(pk.x >> 16))    + a0.y;
    float x2 = h2f((ushort)(pk.y & 0xffff)) + a0.z;
    float x3 = h2f((ushort)(pk.y >> 16))    + a0.w;
    float x4 = h2f((ushort)(pk.z & 0xffff)) + a1.x;
    float x5 = h2f((ushort)(pk.z >> 16))    + a1.y;
    float x6 = h2f((ushort)(pk.w & 0xffff)) + a1.z;
    float x7 = h2f((ushort)(pk.w >> 16))    + a1.w;
    float mx = fmaxf(fmaxf(fmaxf(x0, x1), fmaxf(x2, x3)),
                     fmaxf(fmaxf(x4, x5), fmaxf(x6, x7)));
    float nm = fmaxf(m, mx);
    s = s * __expf(m - nm)
        + __expf(x0 - nm) + __expf(x1 - nm) + __expf(x2 - nm) + __expf(x3 - nm)
        + __expf(x4 - nm) + __expf(x5 - nm) + __expf(x6 - nm) + __expf(x7 - nm);
    m = nm;
}

// ------- quad-row fp16 logsumexp with 16B loads: outv[r] = NORMC - lse_j(...) -------
__global__ __launch_bounds__(256) void lse4h(const ushort* __restrict__ Sh, int lda,
                                             const float* __restrict__ addv,
                                             float* __restrict__ outv, int C, int R) {
    int r0 = blockIdx.x * 4;
    const ushort* rp[4];
    #pragma unroll
    for (int q = 0; q < 4; ++q) {
        int r = r0 + q; if (r >= R) r = R - 1;
        rp[q] = Sh + (size_t)r * lda;
    }
    float m[4], s[4];
    #pragma unroll
    for (int q = 0; q < 4; ++q) { m[q] = -INFINITY; s[q] = 0.0f; }
    int C8 = C >> 3;
    for (int j = threadIdx.x; j < C8; j += 256) {
        float4 a0 = ((const float4*)addv)[(j << 1)];
        float4 a1 = ((const float4*)addv)[(j << 1) + 1];
        #pragma unroll
        for (int q = 0; q < 4; ++q) {
            uint4 pk = *(const uint4*)(rp[q] + (j << 3));
            lse8(pk, a0, a1, m[q], s[q]);
        }
    }
    int rem = C & 7;
    if ((int)threadIdx.x < rem) {
        int j = (C8 << 3) + threadIdx.x;
        float av = addv[j];
        #pragma unroll
        for (int q = 0; q < 4; ++q) {
            float x = h2f(rp[q][j]) + av;
            float nm = fmaxf(m[q], x);
            s[q] = s[q] * __expf(m[q] - nm) + __expf(x - nm);
            m[q] = nm;
        }
    }
    #pragma unroll
    for (int q = 0; q < 4; ++q) wave_lse_reduce(m[q], s[q]);
    __shared__ float sm[4][4], ss[4][4];   // [wave][q]
    int w = threadIdx.x >> 6;
    if ((threadIdx.x & 63) == 0) {
        #pragma unroll
        for (int q = 0; q < 4; ++q) { sm[w][q] = m[q]; ss[w][q] = s[q]; }
    }
    __syncthreads();
    if (threadIdx.x < 4) {
        int q = threadIdx.x;
        float mm = sm[0][q], sa = ss[0][q];
        #pragma unroll
        for (int i = 1; i < 4; ++i) {
            float om = sm[i][q], os = ss[i][q];
            float nm = fmaxf(mm, om);
            sa = sa * __expf(mm - nm) + os * __expf(om - nm);
            mm = nm;
        }
        int r = r0 + q;
        if (r < R) outv[r] = NORMC - (mm + __logf(sa));
    }
}

// ---------- on-the-fly exp from fp16 S: 8 elems -> bf16 hi/lo packed ----------
__device__ __forceinline__ void exp_row8h(const ushort* __restrict__ Sh,
        const float* __restrict__ rowadd, const float* __restrict__ coladd,
        int lda, int M, int gm, int kbase, uint4& hiv, uint4& lov) {
    ushort h[8], l[8];
    if (gm < M) {
        float ra = rowadd[gm] - NORMC;
        const ushort* rp = Sh + (size_t)gm * lda + kbase;
        ushort4 q0 = *(const ushort4*)rp;
        ushort4 q1 = *(const ushort4*)(rp + 4);
        float4 ca = *(const float4*)(coladd + kbase);
        float4 cb = *(const float4*)(coladd + kbase + 4);
        float vv[8] = {h2f(q0.x) + ca.x, h2f(q0.y) + ca.y, h2f(q0.z) + ca.z, h2f(q0.w) + ca.w,
                       h2f(q1.x) + cb.x, h2f(q1.y) + cb.y, h2f(q1.z) + cb.z, h2f(q1.w) + cb.w};
        #pragma unroll
        for (int e = 0; e < 8; ++e) {
            float av = __expf(vv[e] + ra);
            bfsplit(av, h[e], l[e]);
        }
    } else {
        #pragma unroll
        for (int e = 0; e < 8; ++e) { h[e] = 0; l[e] = 0; }
    }
    hiv.x = (unsigned)h[0] | ((unsigned)h[1] << 16);
    hiv.y = (unsigned)h[2] | ((unsigned)h[3] << 16);
    hiv.z = (unsigned)h[4] | ((unsigned)h[5] << 16);
    hiv.w = (unsigned)h[6] | ((unsigned)h[7] << 16);
    lov.x = (unsigned)l[0] | ((unsigned)l[1] << 16);
    lov.y = (unsigned)l[2] | ((unsigned)l[3] << 16);
    lov.z = (unsigned)l[4] | ((unsigned)l[5] << 16);
    lov.w = (unsigned)l[6] | ((unsigned)l[7] << 16);
}

// ============ BIG GEMM: 64 rows x 256 cols (full N), 8 waves (2Mx4N), split-K ============
__global__ __launch_bounds__(512) __attribute__((amdgpu_waves_per_eu(2, 4)))
void gemm_bigN(
        const ushort* __restrict__ Sh, const float* __restrict__ rowadd,
        const float* __restrict__ coladd, int lda,
        const ushort* __restrict__ Bh, const ushort* __restrict__ Bl, int ldb,
        float* __restrict__ P, int M, int K, int Kc) {
    __shared__ __align__(16) ushort SM[2 * 64 * 64 + 2 * 256 * 64];   // 80 KB
    ushort* As0 = SM;
    ushort* As1 = SM + 4096;
    ushort* Bs0 = SM + 8192;
    ushort* Bs1 = SM + 8192 + 16384;
    const int tid = threadIdx.x;
    const int bm = blockIdx.x << 6;
    const int lane = tid & 63;
    const int wv = tid >> 6;
    const int wr = (wv >> 2) << 5;
    const int wc = (wv & 3) << 6;
    const int kb = blockIdx.y * Kc;
    int ke = kb + Kc; if (ke > K) ke = K;
    const int arow = tid >> 3, ak8 = (tid & 7) << 3;
    const int as = ((arow << 6) + ak8) ^ ((arow & 7) << 3);
    const int brow_base = wv << 5;
    f32x4 acc[2][4] = {};
    for (int k0 = kb; k0 < ke; k0 += 64) {
        uint4 ah, al;
        exp_row8h(Sh, rowadd, coladd, lda, M, bm + arow, k0 + ak8, ah, al);
        __syncthreads();
        #pragma unroll
        for (int t = 0; t < 4; ++t) {
            int rb2 = brow_base + (t << 3);
            int row = rb2 + (lane >> 3);
            int kksrc = (((lane & 7) ^ (row & 7)) << 3);
            size_t go = (size_t)row * ldb + k0 + kksrc;
            GLL16(Bh + go, &Bs0[rb2 << 6]);
            GLL16(Bl + go, &Bs1[rb2 << 6]);
        }
        *(uint4*)&As0[as] = ah;
        *(uint4*)&As1[as] = al;
        __syncthreads();
        #pragma unroll
        for (int ks = 0; ks < 2; ++ks) {
            int kq = (ks << 5) + ((lane >> 4) << 3);
            bf16x8 fah[2], fal[2], fbh[4], fbl[4];
            #pragma unroll
            for (int f = 0; f < 2; ++f) {
                int rr = wr + (f << 4) + (lane & 15);
                int ia = ((rr << 6) + kq) ^ ((rr & 7) << 3);
                fah[f] = *(const bf16x8*)&As0[ia];
                fal[f] = *(const bf16x8*)&As1[ia];
            }
            #pragma unroll
            for (int g = 0; g < 4; ++g) {
                int cc = wc + (g << 4) + (lane & 15);
                int ib = ((cc << 6) + kq) ^ ((cc & 7) << 3);
                fbh[g] = *(const bf16x8*)&Bs0[ib];
                fbl[g] = *(const bf16x8*)&Bs1[ib];
            }
            #pragma unroll
            for (int i = 0; i < 2; ++i)
                #pragma unroll
                for (int j = 0; j < 4; ++j) {
                    acc[i][j] = __builtin_amdgcn_mfma_f32_16x16x32_bf16(fah[i], fbh[j], acc[i][j], 0, 0, 0);
                    acc[i][j] = __builtin_amdgcn_mfma_f32_16x16x32_bf16(fah[i], fbl[j], acc[i][j], 0, 0, 0);
                    acc[i][j] = __builtin_amdgcn_mfma_f32_16x16x32_bf16(fal[i], fbh[j], acc[i][j], 0, 0, 0);
                }
        }
    }
    __syncthreads();
    float* LF = (float*)SM;               // [64][256] f32
    #pragma unroll
    for (int i = 0; i < 2; ++i) {
        int row0 = wr + (i << 4) + ((lane >> 4) << 2);
        #pragma unroll
        for (int j = 0; j < 4; ++j) {
            int col = wc + (j << 4) + (lane & 15);
            #pragma unroll
            for (int r = 0; r < 4; ++r)
                LF[(row0 + r) * 256 + col] = acc[i][j][r];
        }
    }
    __syncthreads();
    float* Pp = P + (size_t)blockIdx.y * ((size_t)M * 256);
    #pragma unroll
    for (int it = 0; it < 8; ++it) {
        int idx = tid + (it << 9);
        int row = idx >> 6, c4 = (idx & 63) << 2;
        if (bm + row < M)
            *(float4*)(Pp + (size_t)(bm + row) * 256 + c4) = *(const float4*)&LF[row * 256 + c4];
    }
}

// ============ small split-K split-bf16 MFMA GEMM (64x64 tile) ============
__global__ __launch_bounds__(256) __attribute__((amdgpu_waves_per_eu(4, 8)))
void gemm_ks(
        const ushort* __restrict__ Ah, const ushort* __restrict__ Al, int lda,
        const ushort* __restrict__ Bh, const ushort* __restrict__ Bl, int ldb, int Nb,
        float* __restrict__ P, int M, int Nplane, int K, int Kc) {
    __shared__ __align__(16) ushort SM[4 * 64 * 64];   // 32 KB
    ushort* As0 = SM;
    ushort* As1 = SM + 4096;
    ushort* Bs0 = SM + 8192;
    ushort* Bs1 = SM + 12288;
    const int tid = threadIdx.x;
    const int bm = blockIdx.y << 6, bn = blockIdx.x << 6;
    const int lane = tid & 63;
    const int wv = tid >> 6;
    const int wm = (wv >> 1) << 5, wn = (wv & 1) << 5;
    const int kb = blockIdx.z * Kc;
    int ke = kb + Kc; if (ke > K) ke = K;
    const int rb = wv << 4;
    f32x4 acc[2][2] = {};
    for (int k0 = kb; k0 < ke; k0 += 64) {
        __syncthreads();
        #pragma unroll
        for (int t = 0; t < 2; ++t) {
            int rb2 = rb + (t << 3);
            int row = rb2 + (lane >> 3);
            int kksrc = (((lane & 7) ^ (row & 7)) << 3);
            int ga = bm + row; ga = (ga < M) ? ga : (M - 1);
            int gb = bn + row; gb = (gb < Nb) ? gb : (Nb - 1);
            size_t goa = (size_t)ga * lda + k0 + kksrc;
            size_t gob = (size_t)gb * ldb + k0 + kksrc;
            GLL16(Ah + goa, &As0[rb2 << 6]);
            GLL16(Al + goa, &As1[rb2 << 6]);
            GLL16(Bh + gob, &Bs0[rb2 << 6]);
            GLL16(Bl + gob, &Bs1[rb2 << 6]);
        }
        __syncthreads();
        #pragma unroll
        for (int ks = 0; ks < 2; ++ks) {
            int kbq = (ks << 5) + ((lane >> 4) << 3);
            bf16x8 fah[2], fal[2], fbh[2], fbl[2];
            #pragma unroll
            for (int f = 0; f < 2; ++f) {
                int rr = wm + (f << 4) + (lane & 15);
                int ia = ((rr << 6) + kbq) ^ ((rr & 7) << 3);
                fah[f] = *(const bf16x8*)&As0[ia];
                fal[f] = *(const bf16x8*)&As1[ia];
                int cc = wn + (f << 4) + (lane & 15);
                int ib = ((cc << 6) + kbq) ^ ((cc & 7) << 3);
                fbh[f] = *(const bf16x8*)&Bs0[ib];
                fbl[f] = *(const bf16x8*)&Bs1[ib];
            }
            #pragma unroll
            for (int i = 0; i < 2; ++i)
                #pragma unroll
                for (int j = 0; j < 2; ++j) {
                    acc[i][j] = __builtin_amdgcn_mfma_f32_16x16x32_bf16(fah[i], fbh[j], acc[i][j], 0, 0, 0);
                    acc[i][j] = __builtin_amdgcn_mfma_f32_16x16x32_bf16(fah[i], fbl[j], acc[i][j], 0, 0, 0);
                    acc[i][j] = __builtin_amdgcn_mfma_f32_16x16x32_bf16(fal[i], fbh[j], acc[i][j], 0, 0, 0);
                }
        }
    }
    __syncthreads();
    float* LF = (float*)SM;               // [64][64] f32
    #pragma unroll
    for (int i = 0; i < 2; ++i) {
        int row0 = wm + (i << 4) + ((lane >> 4) << 2);
        #pragma unroll
        for (int j = 0; j < 2; ++j) {
            int col = wn + (j << 4) + (lane & 15);
            #pragma unroll
            for (int r = 0; r < 4; ++r)
                LF[(row0 + r) * 64 + col] = acc[i][j][r];
        }
    }
    __syncthreads();
    float* Pp = P + (size_t)blockIdx.z * ((size_t)M * Nplane);
    #pragma unroll
    for (int it = 0; it < 4; ++it) {
        int idx = tid + (it << 8);
        int row = idx >> 4, c4 = (idx & 15) << 2;
        if (bm + row < M && bn + c4 < Nplane)
            *(float4*)(Pp + (size_t)(bm + row) * Nplane + bn + c4) = *(const float4*)&LF[row * 64 + c4];
    }
}

// ============ dual small GEMM: tuT (B1=hu) and tnT (B2=hn), shared A (gW) ============
// grid (32+63, 4, 2): bx<32 -> B1 tile (Nplane1=UU planes at P1), else B2 (N4P at P2)
__global__ __launch_bounds__(256) __attribute__((amdgpu_waves_per_eu(4, 8)))
void gemm_ks_dual(
        const ushort* __restrict__ Ah, const ushort* __restrict__ Al, int lda,
        const ushort* __restrict__ B1h, const ushort* __restrict__ B1l,
        const ushort* __restrict__ B2h, const ushort* __restrict__ B2l,
        float* __restrict__ P1, float* __restrict__ P2, int K, int Kc) {
    __shared__ __align__(16) ushort SM[4 * 64 * 64];
    ushort* As0 = SM;
    ushort* As1 = SM + 4096;
    ushort* Bs0 = SM + 8192;
    ushort* Bs1 = SM + 12288;
    const int tid = threadIdx.x;
    const bool second = (blockIdx.x >= 32);
    const int bn = (second ? (blockIdx.x - 32) : blockIdx.x) << 6;
    const int bm = blockIdx.y << 6;
    const ushort* Bh = second ? B2h : B1h;
    const ushort* Bl = second ? B2l : B1l;
    const int Nb = second ? NN : UU;
    const int Nplane = second ? N4P : UU;
    float* P = second ? P2 : P1;
    const int M = 256, ldb = 256;
    const int lane = tid & 63;
    const int wv = tid >> 6;
    const int wm = (wv >> 1) << 5, wn = (wv & 1) << 5;
    const int kb = blockIdx.z * Kc;
    int ke = kb + Kc; if (ke > K) ke = K;
    const int rb = wv << 4;
    f32x4 acc[2][2] = {};
    for (int k0 = kb; k0 < ke; k0 += 64) {
        __syncthreads();
        #pragma unroll
        for (int t = 0; t < 2; ++t) {
            int rb2 = rb + (t << 3);
            int row = rb2 + (lane >> 3);
            int kksrc = (((lane & 7) ^ (row & 7)) << 3);
            int ga = bm + row;                       // M=256, always valid
            int gb = bn + row; gb = (gb < Nb) ? gb : (Nb - 1);
            size_t goa = (size_t)ga * lda + k0 + kksrc;
            size_t gob = (size_t)gb * ldb + k0 + kksrc;
            GLL16(Ah + goa, &As0[rb2 << 6]);
            GLL16(Al + goa, &As1[rb2 << 6]);
            GLL16(Bh + gob, &Bs0[rb2 << 6]);
            GLL16(Bl + gob, &Bs1[rb2 << 6]);
        }
        __syncthreads();
        #pragma unroll
        for (int ks = 0; ks < 2; ++ks) {
            int kbq = (ks << 5) + ((lane >> 4) << 3);
            bf16x8 fah[2], fal[2], fbh[2], fbl[2];
            #pragma unroll
            for (int f = 0; f < 2; ++f) {
                int rr = wm + (f << 4) + (lane & 15);
                int ia = ((rr << 6) + kbq) ^ ((rr & 7) << 3);
                fah[f] = *(const bf16x8*)&As0[ia];
                fal[f] = *(const bf16x8*)&As1[ia];
                int cc = wn + (f << 4) + (lane & 15);
                int ib = ((cc << 6) + kbq) ^ ((cc & 7) << 3);
                fbh[f] = *(const bf16x8*)&Bs0[ib];
                fbl[f] = *(const bf16x8*)&Bs1[ib];
            }
            #pragma unroll
            for (int i = 0; i < 2; ++i)
                #pragma unroll
                for (int j = 0; j < 2; ++j) {
                    acc[i][j] = __builtin_amdgcn_mfma_f32_16x16x32_bf16(fah[i], fbh[j], acc[i][j], 0, 0, 0);
                    acc[i][j] = __builtin_amdgcn_mfma_f32_16x16x32_bf16(fah[i], fbl[j], acc[i][j], 0, 0, 0);
                    acc[i][j] = __builtin_amdgcn_mfma_f32_16x16x32_bf16(fal[i], fbh[j], acc[i][j], 0, 0, 0);
                }
        }
    }
    __syncthreads();
    float* LF = (float*)SM;
    #pragma unroll
    for (int i = 0; i < 2; ++i) {
        int row0 = wm + (i << 4) + ((lane >> 4) << 2);
        #pragma unroll
        for (int j = 0; j < 2; ++j) {
            int col = wn + (j << 4) + (lane & 15);
            #pragma unroll
            for (int r = 0; r < 4; ++r)
                LF[(row0 + r) * 64 + col] = acc[i][j][r];
        }
    }
    __syncthreads();
    float* Pp = P + (size_t)blockIdx.z * ((size_t)M * Nplane);
    #pragma unroll
    for (int it = 0; it < 4; ++it) {
        int idx = tid + (it << 8);
        int row = idx >> 4, c4 = (idx & 15) << 2;
        if (bn + c4 < Nplane)
            *(float4*)(Pp + (size_t)(bm + row) * Nplane + bn + c4) = *(const float4*)&LF[row * 64 + c4];
    }
}

// ---- dual reduce: tuT from P1 (zg=2), tnT from P2 (zg=2), both -> bf16 pairs ----
__global__ __launch_bounds__(256) void reduce_dual(
        const float* __restrict__ P1, const float* __restrict__ P2,
        ushort* __restrict__ T1h, ushort* __restrict__ T1l,
        ushort* __restrict__ T2h, ushort* __restrict__ T2l) {
    const int tot1 = 256 * (UU >> 2);
    const int tot2 = 256 * (N4P >> 2);
    int t = blockIdx.x * 256 + threadIdx.x;
    const float* P; int m, n, Npl, ldo; ushort *Ch, *Cl;
    if (t < tot1) {
        m = t / (UU >> 2); n = (t - m * (UU >> 2)) << 2;
        P = P1; Npl = UU; ldo = UU; Ch = T1h; Cl = T1l;
    } else {
        t -= tot1;
        if (t >= tot2) return;
        m = t / (N4P >> 2); n = (t - m * (N4P >> 2)) << 2;
        P = P2; Npl = N4P; ldo = KP; Ch = T2h; Cl = T2l;
    }
    size_t pstr = (size_t)256 * Npl;
    const float* base = P + (size_t)m * Npl + n;
    float4 a = *(const float4*)base;
    float4 b = *(const float4*)(base + pstr);
    a.x += b.x; a.y += b.y; a.z += b.z; a.w += b.w;
    ushort4 hv, lv;
    bfsplit(a.x, hv.x, lv.x); bfsplit(a.y, hv.y, lv.y);
    bfsplit(a.z, hv.z, lv.z); bfsplit(a.w, hv.w, lv.w);
    size_t co = (size_t)m * ldo + n;
    *(ushort4*)(Ch + co) = hv;
    *(ushort4*)(Cl + co) = lv;
}

// ---- reduce planes + epilogue: C = act(sum_z P[z] + bias + res) ----
template<int ACT, int BIAS, int RES, int OUTK>
__global__ __launch_bounds__(256) void reduce_ks(
        const float* __restrict__ P, int zg,
        const float* __restrict__ bias,
        const ushort* __restrict__ Rh, const ushort* __restrict__ Rl,
        float* __restrict__ Cf, ushort* __restrict__ Ch, ushort* __restrict__ Cl,
        int M, int N4, int ldo) {
    int t = blockIdx.x * 256 + threadIdx.x;
    int n4w = N4 >> 2;
    int tot = M * n4w;
    if (t >= tot) return;
    int m = t / n4w;
    int n = (t - m * n4w) << 2;
    size_t pstr = (size_t)M * N4;
    const float* base = P + (size_t)m * N4 + n;
    float4 a = *(const float4*)base;
    for (int z = 1; z < zg; ++z) {
        float4 b = *(const float4*)(base + (size_t)z * pstr);
        a.x += b.x; a.y += b.y; a.z += b.z; a.w += b.w;
    }
    if (BIAS == 1) {
        float4 bv = *(const float4*)(bias + n);
        a.x += bv.x; a.y += bv.y; a.z += bv.z; a.w += bv.w;
    }
    if (BIAS == 2) {
        float s = bias[m];
        a.x += s; a.y += s; a.z += s; a.w += s;
    }
    if (RES) {
        size_t ro = (size_t)m * ldo + n;
        ushort4 rh = *(const ushort4*)(Rh + ro);
        ushort4 rl = *(const ushort4*)(Rl + ro);
        a.x += bf2f(rh.x) + bf2f(rl.x); a.y += bf2f(rh.y) + bf2f(rl.y);
        a.z += bf2f(rh.z) + bf2f(rl.z); a.w += bf2f(rh.w) + bf2f(rl.w);
    }
    if (ACT == 1) {
        a.x = fmaxf(a.x, 0.f); a.y = fmaxf(a.y, 0.f);
        a.z = fmaxf(a.z, 0.f); a.w = fmaxf(a.w, 0.f);
    }
    if (ACT == 2) {
        a.x = tanhf(a.x); a.y = tanhf(a.y); a.z = tanhf(a.z); a.w = tanhf(a.w);
    }
    size_t co = (size_t)m * ldo + n;
    if (OUTK == 0) {
        *(float4*)(Cf + co) = a;
    } else {
        ushort4 hv, lv;
        bfsplit(a.x, hv.x, lv.x); bfsplit(a.y, hv.y, lv.y);
        bfsplit(a.z, hv.z, lv.z); bfsplit(a.w, hv.w, lv.w);
        *(ushort4*)(Ch + co) = hv;
        *(ushort4*)(Cl + co) = lv;
    }
}

static inline int rgrid(int M, int N4) { return (M * (N4 >> 2) + 255) / 256; }

extern "C" void kernel_launch(void* const* d_in, const int* in_sizes, int n_in,
                              void* d_out, int out_size, void* d_ws, size_t ws_size,
                              hipStream_t stream) {
    const float* dsf = (const float*)d_in[0];
    const float* unl = (const float*)d_in[1];
    const float* S   = (const float*)d_in[2];
    const float* Wb  = (const float*)d_in[3];
    const float* bb  = (const float*)d_in[4];
    const float* gcW[3] = {(const float*)d_in[5], (const float*)d_in[7], (const float*)d_in[9]};
    const float* gcb[3] = {(const float*)d_in[6], (const float*)d_in[8], (const float*)d_in[10]};
    const float* W1 = (const float*)d_in[11];
    const float* b1 = (const float*)d_in[12];
    const float* W2 = (const float*)d_in[13];
    const float* b2 = (const float*)d_in[14];
    float* out = (float*)d_out;

    // -------- workspace carve --------
    char* p = (char*)d_ws;
    ushort* Shm = (ushort*)p; p += (size_t)NN * UU * 2;                // 16.4 MB fp16 S
    ushort* STh = (ushort*)p; p += (size_t)UU * KP * 2;                // 16.5 MB fp16 S^T
    float* P    = (float*)p;  p += (size_t)8 * NN * 256 * 4;           // 32.8 MB planes
    ushort* fh = (ushort*)p; ushort* fl = fh + (size_t)NN * 256; p += (size_t)NN * 256 * 4;
    ushort* xh = (ushort*)p; ushort* xl = xh + (size_t)NN * 256; p += (size_t)NN * 256 * 4;
    ushort* xTh = (ushort*)p; ushort* xTl = xTh + (size_t)256 * KP; p += (size_t)256 * KP * 4;
    ushort* huh = (ushort*)p; ushort* hul = huh + (size_t)UU * 256; p += (size_t)UU * 256 * 4;
    ushort* tuTh = (ushort*)p; ushort* tuTl = tuTh + (size_t)256 * UU; p += (size_t)256 * UU * 4;
    ushort* tnTh = (ushort*)p; ushort* tnTl = tnTh + (size_t)256 * KP; p += (size_t)256 * KP * 4;
    float* u_ext = (float*)p; p += KP * 4;
    float* v     = (float*)p; p += UU * 4;
    ushort* WbTh = (ushort*)p; ushort* WbTl = WbTh + 256 * 256; p += 256 * 256 * 4;
    ushort* gWh[3]; ushort* gWl[3];
    for (int l = 0; l < 3; ++l) { gWh[l] = (ushort*)p; gWl[l] = gWh[l] + 256 * 256; p += 256 * 256 * 4; }
    ushort* W1Th = (ushort*)p; ushort* W1Tl = W1Th + 512 * 256; p += 512 * 256 * 4;
    ushort* W2Th = (ushort*)p; ushort* W2Tl = W2Th + 256 * 512; p += 256 * 512 * 4;
    // dual-GEMM plane regions inside P
    float* P1 = P;
    float* P2 = P + (size_t)2 * 256 * UU;
    // h1 pair aliases x + start of xT region (both dead by head time)
    ushort* h1h = xh; ushort* h1l = h1h + (size_t)UU * 512;
    (void)ws_size;

    // -------- prep --------
    concat_bf<<<dim3(1004), dim3(256), 0, stream>>>(dsf, unl, fh, fl, u_ext, v);
    convW_all<<<dim3(16, 16, 6), dim3(32, 8), 0, stream>>>(
        Wb, gcW[0], gcW[1], gcW[2], W1, W2,
        WbTh, WbTl, gWh[0], gWl[0], gWh[1], gWl[1], gWh[2], gWl[2],
        W1Th, W1Tl, W2Th, W2Tl);
    conv_both<<<dim3(64, 126), dim3(32, 8), 0, stream>>>(S, Shm, STh);

    // x = relu(feats @ Wb + bb)  [NN][256]
    gemm_ks<<<dim3(4, 63, 2), 256, 0, stream>>>(
        fh, fl, 256, WbTh, WbTl, 256, 256, P, NN, 256, 256, 128);
    reduce_ks<1,1,0,1><<<rgrid(NN,256), 256, 0, stream>>>(
        P, 2, bb, nullptr, nullptr, nullptr, xh, xl, NN, 256, 256);
    // xT = x^T  [256][KP]
    gemm_ks<<<dim3(63, 4, 2), 256, 0, stream>>>(
        WbTh, WbTl, 256, fh, fl, 256, NN, P, 256, N4P, 256, 128);
    reduce_ks<1,2,0,1><<<rgrid(256,N4P), 256, 0, stream>>>(
        P, 2, bb, nullptr, nullptr, nullptr, xTh, xTl, 256, N4P, KP);

    // -------- Sinkhorn (fp16 S, f32 math): 40 small launches --------
    // (R10: grid.sync ~25us/sync; R13: per-block __threadfence ~L2-writeback — both lose
    //  to graph-replayed launches. Keep the 40-launch loop.)
    for (int it = 0; it < 20; ++it) {
        lse4h<<<dim3((NN + 3) / 4), dim3(256), 0, stream>>>(Shm, UU, v, u_ext, UU, NN);
        lse4h<<<dim3(UU / 4),       dim3(256), 0, stream>>>(STh, KP, u_ext, v, NN, UU);
    }

    // -------- G1: hu0 = A^T @ x  [UU][256] --------
    gemm_bigN<<<dim3(32, 8), 512, 0, stream>>>(
        STh, v, u_ext, KP, xTh, xTl, KP, P, UU, KP, 512);
    reduce_ks<0,0,0,1><<<rgrid(UU,256), 256, 0, stream>>>(
        P, 8, nullptr, nullptr, nullptr, nullptr, huh, hul, UU, 256, 256);

    // -------- 3 GCN layers --------
    const int dual_grid = (256 * (UU >> 2) + 256 * (N4P >> 2) + 255) / 256;
    for (int l = 0; l < 3; ++l) {
        const ushort* hnh = (l == 0) ? xh : fh;
        const ushort* hnl = (l == 0) ? xl : fl;
        if (l < 2) {
            // tuT + tnT in one launch (shared A = gW)
            gemm_ks_dual<<<dim3(95, 4, 2), 256, 0, stream>>>(
                gWh[l], gWl[l], 256, huh, hul, hnh, hnl, P1, P2, 256, 128);
            reduce_dual<<<dim3(dual_grid), 256, 0, stream>>>(
                P1, P2, tuTh, tuTl, tnTh, tnTl);
        } else {
            gemm_ks<<<dim3(63, 4, 2), 256, 0, stream>>>(
                gWh[l], gWl[l], 256, hnh, hnl, 256, NN, P, 256, N4P, 256, 128);
            reduce_ks<0,0,0,1><<<rgrid(256,N4P), 256, 0, stream>>>(
                P, 2, nullptr, nullptr, nullptr, nullptr, tnTh, tnTl, 256, N4P, KP);
        }
        if (l < 2) {
            // hn_next = tanh(A @ t_u + b + hn), z=6
            gemm_bigN<<<dim3(63, 6), 512, 0, stream>>>(
                Shm, u_ext, v, UU, tuTh, tuTl, UU, P, NN, UU, 384);
            reduce_ks<2,1,1,1><<<rgrid(NN,256), 256, 0, stream>>>(
                P, 6, gcb[l], hnh, hnl, nullptr, fh, fl, NN, 256, 256);
        }
        // hu_next = tanh(A^T @ t_n + b + hu)
        gemm_bigN<<<dim3(32, 8), 512, 0, stream>>>(
            STh, v, u_ext, KP, tnTh, tnTl, KP, P, UU, KP, 512);
        reduce_ks<2,1,1,1><<<rgrid(UU,256), 256, 0, stream>>>(
            P, 8, gcb[l], huh, hul, nullptr, huh, hul, UU, 256, 256);
    }

    // -------- head --------
    gemm_ks<<<dim3(8, 32, 2), 256, 0, stream>>>(
        huh, hul, 256, W1Th, W1Tl, 256, 512, P, UU, 512, 256, 128);
    reduce_ks<1,1,0,1><<<rgrid(UU,512), 256, 0, stream>>>(
        P, 2, b1, nullptr, nullptr, nullptr, h1h, h1l, UU, 512, 512);
    gemm_ks<<<dim3(4, 32, 4), 256, 0, stream>>>(
        h1h, h1l, 512, W2Th, W2Tl, 512, 256, P, UU, 256, 512, 128);
    reduce_ks<0,1,0,0><<<rgrid(UU,256), 256, 0, stream>>>(
        P, 4, b2, nullptr, nullptr, out, nullptr, nullptr, UU, 256, 256);
}

// Round 15
// 519.278 us; speedup vs baseline: 3.3312x; 1.0292x over previous
//
#include <hip/hip_runtime.h>
#include <hip/hip_fp16.h>
#include <math.h>

#define NN 4003              // label nodes
#define UU 2048              // unify nodes
#define KP 4032              // node dim padded to multiple of 64
#define N4P 4004             // NN rounded up to multiple of 4 (plane width)
#define NORMC (-8.7079796f)  // -log(4003+2048)

using bf16x8 = __attribute__((ext_vector_type(8))) short;
using f32x4  = __attribute__((ext_vector_type(4))) float;

// async global->LDS, 16B per lane; dest is wave-uniform base + lane*16
#define GLL16(g, l) __builtin_amdgcn_global_load_lds( \
    (const __attribute__((address_space(1))) unsigned*)(g), \
    (__attribute__((address_space(3))) unsigned*)(l), 16, 0, 0)

__device__ __forceinline__ ushort f2bf(float x) {
    unsigned u = __builtin_bit_cast(unsigned, x);
    u += 0x7fff + ((u >> 16) & 1);
    return (ushort)(u >> 16);
}
__device__ __forceinline__ float bf2f(ushort h) {
    unsigned u = ((unsigned)h) << 16;
    return __builtin_bit_cast(float, u);
}
__device__ __forceinline__ void bfsplit(float x, ushort& hi, ushort& lo) {
    hi = f2bf(x);
    lo = f2bf(x - bf2f(hi));
}
__device__ __forceinline__ float h2f(ushort h) {
    return __half2float(__ushort_as_half(h));
}

// ---------- concat + bf16 hi/lo split; tail blocks zero v and init u_ext pad ----------
__global__ void concat_bf(const float* __restrict__ a, const float* __restrict__ b,
                          ushort* __restrict__ fh, ushort* __restrict__ fl,
                          float* __restrict__ u_ext, float* __restrict__ v) {
    int bid = blockIdx.x;
    if (bid >= 1001) {
        if (bid < 1003) {                       // zero v: 512 float4
            int t = (bid - 1001) * 256 + threadIdx.x;
            if (t < 512) ((float4*)v)[t] = (float4){0.f, 0.f, 0.f, 0.f};
        } else {                                // u_ext pad
            if ((int)threadIdx.x < KP - NN) u_ext[NN + threadIdx.x] = -1e30f;
        }
        return;
    }
    int i = bid * 256 + threadIdx.x;
    const int tot4 = NN * 256 / 4;
    if (i >= tot4) return;
    float4 vv = (i < 256000) ? ((const float4*)a)[i] : ((const float4*)b)[i - 256000];
    ushort4 hv, lv;
    bfsplit(vv.x, hv.x, lv.x); bfsplit(vv.y, hv.y, lv.y);
    bfsplit(vv.z, hv.z, lv.z); bfsplit(vv.w, hv.w, lv.w);
    *(ushort4*)(fh + ((size_t)i << 2)) = hv;
    *(ushort4*)(fl + ((size_t)i << 2)) = lv;
}

// ---------- batched weight convert: 6 weights, blockIdx.z selects ----------
__global__ void convW_all(
        const float* __restrict__ Wa, const float* __restrict__ Wb_,
        const float* __restrict__ Wc, const float* __restrict__ Wd,
        const float* __restrict__ We, const float* __restrict__ Wf,
        ushort* T0h, ushort* T0l, ushort* T1h, ushort* T1l,
        ushort* T2h, ushort* T2l, ushort* T3h, ushort* T3l,
        ushort* T4h, ushort* T4l, ushort* T5h, ushort* T5l) {
    __shared__ float tile[32][33];
    const float* W; ushort* Th; ushort* Tl; int K, Nw;
    switch (blockIdx.z) {
        case 0:  W = Wa;  Th = T0h; Tl = T0l; K = 256; Nw = 256; break;
        case 1:  W = Wb_; Th = T1h; Tl = T1l; K = 256; Nw = 256; break;
        case 2:  W = Wc;  Th = T2h; Tl = T2l; K = 256; Nw = 256; break;
        case 3:  W = Wd;  Th = T3h; Tl = T3l; K = 256; Nw = 256; break;
        case 4:  W = We;  Th = T4h; Tl = T4l; K = 256; Nw = 512; break;
        default: W = Wf;  Th = T5h; Tl = T5l; K = 512; Nw = 256; break;
    }
    int bx = blockIdx.x, by = blockIdx.y;
    if (bx * 32 >= Nw || by * 32 >= K) return;
    int tx = threadIdx.x;
    for (int r = threadIdx.y; r < 32; r += 8)
        tile[r][tx] = W[(size_t)(by * 32 + r) * Nw + bx * 32 + tx];
    __syncthreads();
    for (int r = threadIdx.y; r < 32; r += 8) {
        int n = bx * 32 + r, k = by * 32 + tx;
        ushort hi, lo; bfsplit(tile[tx][r], hi, lo);
        Th[(size_t)n * K + k] = hi;
        Tl[(size_t)n * K + k] = lo;
    }
}

// ---------- S f32 -> Shm fp16 [NN][UU] AND STh fp16 [UU][KP], one read of S ----------
__global__ void conv_both(const float* __restrict__ in, ushort* __restrict__ Sh,
                          ushort* __restrict__ STh) {
    __shared__ float tile[32][33];
    int x = blockIdx.x * 32 + threadIdx.x;       // UU dim
    int y0 = blockIdx.y * 32;                    // NN dim
    for (int r = threadIdx.y; r < 32; r += 8) {
        int y = y0 + r;
        float vv = (y < NN) ? in[(size_t)y * UU + x] : 0.0f;
        tile[r][threadIdx.x] = vv;
        if (y < NN)
            Sh[(size_t)y * UU + x] = __half_as_ushort(__float2half(vv));
    }
    __syncthreads();
    int oc = y0 + threadIdx.x;
    for (int r = threadIdx.y; r < 32; r += 8) {
        int orow = blockIdx.x * 32 + r;
        STh[(size_t)orow * KP + oc] = __half_as_ushort(__float2half(tile[threadIdx.x][r]));
    }
}

__device__ __forceinline__ void wave_lse_reduce(float& m, float& s) {
    #pragma unroll
    for (int off = 1; off < 64; off <<= 1) {
        float om = __shfl_xor(m, off, 64), os = __shfl_xor(s, off, 64);
        float nm = fmaxf(m, om);
        s = s * __expf(m - nm) + os * __expf(om - nm);
        m = nm;
    }
}
__device__ __forceinline__ void lse8(uint4 pk, float4 a0, float4 a1, float& m, float& s) {
    float x0 = h2f((ushort)(pk.x & 0xffff)) + a0.x;
    float x1 = h2f((ushort)(pk.x >> 16))    + a0.y;
    float x2 = h2f((ushort)(pk.y & 0xffff)) + a0.z;
    float x3 = h2f((ushort)(pk.y >> 16))    + a0.w;
    float x4 = h2f((ushort)(pk.z & 0xffff)) + a1.x;
    float x5 = h2f((ushort)(pk.z >> 16))    + a1.y;
    float x6 = h2f((ushort)(pk.w & 0xffff)) + a1.z;
    float x7 = h2f((ushort)(pk.w >> 16))    + a1.w;
    float mx = fmaxf(fmaxf(fmaxf(x0, x1), fmaxf(x2, x3)),
                     fmaxf(fmaxf(x4, x5), fmaxf(x6, x7)));
    float nm = fmaxf(m, mx);
    s = s * __expf(m - nm)
        + __expf(x0 - nm) + __expf(x1 - nm) + __expf(x2 - nm) + __expf(x3 - nm)
        + __expf(x4 - nm) + __expf(x5 - nm) + __expf(x6 - nm) + __expf(x7 - nm);
    m = nm;
}

// ------- quad-row fp16 logsumexp with 16B loads: outv[r] = NORMC - lse_j(...) -------
__global__ __launch_bounds__(256) void lse4h(const ushort* __restrict__ Sh, int lda,
                                             const float* __restrict__ addv,
                                             float* __restrict__ outv, int C, int R) {
    int r0 = blockIdx.x * 4;
    const ushort* rp[4];
    #pragma unroll
    for (int q = 0; q < 4; ++q) {
        int r = r0 + q; if (r >= R) r = R - 1;
        rp[q] = Sh + (size_t)r * lda;
    }
    float m[4], s[4];
    #pragma unroll
    for (int q = 0; q < 4; ++q) { m[q] = -INFINITY; s[q] = 0.0f; }
    int C8 = C >> 3;
    for (int j = threadIdx.x; j < C8; j += 256) {
        float4 a0 = ((const float4*)addv)[(j << 1)];
        float4 a1 = ((const float4*)addv)[(j << 1) + 1];
        #pragma unroll
        for (int q = 0; q < 4; ++q) {
            uint4 pk = *(const uint4*)(rp[q] + (j << 3));
            lse8(pk, a0, a1, m[q], s[q]);
        }
    }
    int rem = C & 7;
    if ((int)threadIdx.x < rem) {
        int j = (C8 << 3) + threadIdx.x;
        float av = addv[j];
        #pragma unroll
        for (int q = 0; q < 4; ++q) {
            float x = h2f(rp[q][j]) + av;
            float nm = fmaxf(m[q], x);
            s[q] = s[q] * __expf(m[q] - nm) + __expf(x - nm);
            m[q] = nm;
        }
    }
    #pragma unroll
    for (int q = 0; q < 4; ++q) wave_lse_reduce(m[q], s[q]);
    __shared__ float sm[4][4], ss[4][4];   // [wave][q]
    int w = threadIdx.x >> 6;
    if ((threadIdx.x & 63) == 0) {
        #pragma unroll
        for (int q = 0; q < 4; ++q) { sm[w][q] = m[q]; ss[w][q] = s[q]; }
    }
    __syncthreads();
    if (threadIdx.x < 4) {
        int q = threadIdx.x;
        float mm = sm[0][q], sa = ss[0][q];
        #pragma unroll
        for (int i = 1; i < 4; ++i) {
            float om = sm[i][q], os = ss[i][q];
            float nm = fmaxf(mm, om);
            sa = sa * __expf(mm - nm) + os * __expf(om - nm);
            mm = nm;
        }
        int r = r0 + q;
        if (r < R) outv[r] = NORMC - (mm + __logf(sa));
    }
}

// ---------- on-the-fly exp from fp16 S: 8 elems -> bf16 hi/lo packed ----------
__device__ __forceinline__ void exp_row8h(const ushort* __restrict__ Sh,
        const float* __restrict__ rowadd, const float* __restrict__ coladd,
        int lda, int M, int gm, int kbase, uint4& hiv, uint4& lov) {
    ushort h[8], l[8];
    if (gm < M) {
        float ra = rowadd[gm] - NORMC;
        const ushort* rp = Sh + (size_t)gm * lda + kbase;
        ushort4 q0 = *(const ushort4*)rp;
        ushort4 q1 = *(const ushort4*)(rp + 4);
        float4 ca = *(const float4*)(coladd + kbase);
        float4 cb = *(const float4*)(coladd + kbase + 4);
        float vv[8] = {h2f(q0.x) + ca.x, h2f(q0.y) + ca.y, h2f(q0.z) + ca.z, h2f(q0.w) + ca.w,
                       h2f(q1.x) + cb.x, h2f(q1.y) + cb.y, h2f(q1.z) + cb.z, h2f(q1.w) + cb.w};
        #pragma unroll
        for (int e = 0; e < 8; ++e) {
            float av = __expf(vv[e] + ra);
            bfsplit(av, h[e], l[e]);
        }
    } else {
        #pragma unroll
        for (int e = 0; e < 8; ++e) { h[e] = 0; l[e] = 0; }
    }
    hiv.x = (unsigned)h[0] | ((unsigned)h[1] << 16);
    hiv.y = (unsigned)h[2] | ((unsigned)h[3] << 16);
    hiv.z = (unsigned)h[4] | ((unsigned)h[5] << 16);
    hiv.w = (unsigned)h[6] | ((unsigned)h[7] << 16);
    lov.x = (unsigned)l[0] | ((unsigned)l[1] << 16);
    lov.y = (unsigned)l[2] | ((unsigned)l[3] << 16);
    lov.z = (unsigned)l[4] | ((unsigned)l[5] << 16);
    lov.w = (unsigned)l[6] | ((unsigned)l[7] << 16);
}

// ============ BIG GEMM: 64 rows x 256 cols (full N), 8 waves (2Mx4N), split-K ============
// 80 KB LDS -> exactly 2 blocks/CU; grids sized to >= 2 blocks/CU (z raised R15).
__global__ __launch_bounds__(512) __attribute__((amdgpu_waves_per_eu(2, 4)))
void gemm_bigN(
        const ushort* __restrict__ Sh, const float* __restrict__ rowadd,
        const float* __restrict__ coladd, int lda,
        const ushort* __restrict__ Bh, const ushort* __restrict__ Bl, int ldb,
        float* __restrict__ P, int M, int K, int Kc) {
    __shared__ __align__(16) ushort SM[2 * 64 * 64 + 2 * 256 * 64];   // 80 KB
    ushort* As0 = SM;
    ushort* As1 = SM + 4096;
    ushort* Bs0 = SM + 8192;
    ushort* Bs1 = SM + 8192 + 16384;
    const int tid = threadIdx.x;
    const int bm = blockIdx.x << 6;
    const int lane = tid & 63;
    const int wv = tid >> 6;
    const int wr = (wv >> 2) << 5;
    const int wc = (wv & 3) << 6;
    const int kb = blockIdx.y * Kc;
    int ke = kb + Kc; if (ke > K) ke = K;
    const int arow = tid >> 3, ak8 = (tid & 7) << 3;
    const int as = ((arow << 6) + ak8) ^ ((arow & 7) << 3);
    const int brow_base = wv << 5;
    f32x4 acc[2][4] = {};
    for (int k0 = kb; k0 < ke; k0 += 64) {
        uint4 ah, al;
        exp_row8h(Sh, rowadd, coladd, lda, M, bm + arow, k0 + ak8, ah, al);
        __syncthreads();
        #pragma unroll
        for (int t = 0; t < 4; ++t) {
            int rb2 = brow_base + (t << 3);
            int row = rb2 + (lane >> 3);
            int kksrc = (((lane & 7) ^ (row & 7)) << 3);
            size_t go = (size_t)row * ldb + k0 + kksrc;
            GLL16(Bh + go, &Bs0[rb2 << 6]);
            GLL16(Bl + go, &Bs1[rb2 << 6]);
        }
        *(uint4*)&As0[as] = ah;
        *(uint4*)&As1[as] = al;
        __syncthreads();
        #pragma unroll
        for (int ks = 0; ks < 2; ++ks) {
            int kq = (ks << 5) + ((lane >> 4) << 3);
            bf16x8 fah[2], fal[2], fbh[4], fbl[4];
            #pragma unroll
            for (int f = 0; f < 2; ++f) {
                int rr = wr + (f << 4) + (lane & 15);
                int ia = ((rr << 6) + kq) ^ ((rr & 7) << 3);
                fah[f] = *(const bf16x8*)&As0[ia];
                fal[f] = *(const bf16x8*)&As1[ia];
            }
            #pragma unroll
            for (int g = 0; g < 4; ++g) {
                int cc = wc + (g << 4) + (lane & 15);
                int ib = ((cc << 6) + kq) ^ ((cc & 7) << 3);
                fbh[g] = *(const bf16x8*)&Bs0[ib];
                fbl[g] = *(const bf16x8*)&Bs1[ib];
            }
            #pragma unroll
            for (int i = 0; i < 2; ++i)
                #pragma unroll
                for (int j = 0; j < 4; ++j) {
                    acc[i][j] = __builtin_amdgcn_mfma_f32_16x16x32_bf16(fah[i], fbh[j], acc[i][j], 0, 0, 0);
                    acc[i][j] = __builtin_amdgcn_mfma_f32_16x16x32_bf16(fah[i], fbl[j], acc[i][j], 0, 0, 0);
                    acc[i][j] = __builtin_amdgcn_mfma_f32_16x16x32_bf16(fal[i], fbh[j], acc[i][j], 0, 0, 0);
                }
        }
    }
    __syncthreads();
    float* LF = (float*)SM;               // [64][256] f32
    #pragma unroll
    for (int i = 0; i < 2; ++i) {
        int row0 = wr + (i << 4) + ((lane >> 4) << 2);
        #pragma unroll
        for (int j = 0; j < 4; ++j) {
            int col = wc + (j << 4) + (lane & 15);
            #pragma unroll
            for (int r = 0; r < 4; ++r)
                LF[(row0 + r) * 256 + col] = acc[i][j][r];
        }
    }
    __syncthreads();
    float* Pp = P + (size_t)blockIdx.y * ((size_t)M * 256);
    #pragma unroll
    for (int it = 0; it < 8; ++it) {
        int idx = tid + (it << 9);
        int row = idx >> 6, c4 = (idx & 63) << 2;
        if (bm + row < M)
            *(float4*)(Pp + (size_t)(bm + row) * 256 + c4) = *(const float4*)&LF[row * 256 + c4];
    }
}

// ============ small split-K split-bf16 MFMA GEMM (64x64 tile) ============
__global__ __launch_bounds__(256) __attribute__((amdgpu_waves_per_eu(4, 8)))
void gemm_ks(
        const ushort* __restrict__ Ah, const ushort* __restrict__ Al, int lda,
        const ushort* __restrict__ Bh, const ushort* __restrict__ Bl, int ldb, int Nb,
        float* __restrict__ P, int M, int Nplane, int K, int Kc) {
    __shared__ __align__(16) ushort SM[4 * 64 * 64];   // 32 KB
    ushort* As0 = SM;
    ushort* As1 = SM + 4096;
    ushort* Bs0 = SM + 8192;
    ushort* Bs1 = SM + 12288;
    const int tid = threadIdx.x;
    const int bm = blockIdx.y << 6, bn = blockIdx.x << 6;
    const int lane = tid & 63;
    const int wv = tid >> 6;
    const int wm = (wv >> 1) << 5, wn = (wv & 1) << 5;
    const int kb = blockIdx.z * Kc;
    int ke = kb + Kc; if (ke > K) ke = K;
    const int rb = wv << 4;
    f32x4 acc[2][2] = {};
    for (int k0 = kb; k0 < ke; k0 += 64) {
        __syncthreads();
        #pragma unroll
        for (int t = 0; t < 2; ++t) {
            int rb2 = rb + (t << 3);
            int row = rb2 + (lane >> 3);
            int kksrc = (((lane & 7) ^ (row & 7)) << 3);
            int ga = bm + row; ga = (ga < M) ? ga : (M - 1);
            int gb = bn + row; gb = (gb < Nb) ? gb : (Nb - 1);
            size_t goa = (size_t)ga * lda + k0 + kksrc;
            size_t gob = (size_t)gb * ldb + k0 + kksrc;
            GLL16(Ah + goa, &As0[rb2 << 6]);
            GLL16(Al + goa, &As1[rb2 << 6]);
            GLL16(Bh + gob, &Bs0[rb2 << 6]);
            GLL16(Bl + gob, &Bs1[rb2 << 6]);
        }
        __syncthreads();
        #pragma unroll
        for (int ks = 0; ks < 2; ++ks) {
            int kbq = (ks << 5) + ((lane >> 4) << 3);
            bf16x8 fah[2], fal[2], fbh[2], fbl[2];
            #pragma unroll
            for (int f = 0; f < 2; ++f) {
                int rr = wm + (f << 4) + (lane & 15);
                int ia = ((rr << 6) + kbq) ^ ((rr & 7) << 3);
                fah[f] = *(const bf16x8*)&As0[ia];
                fal[f] = *(const bf16x8*)&As1[ia];
                int cc = wn + (f << 4) + (lane & 15);
                int ib = ((cc << 6) + kbq) ^ ((cc & 7) << 3);
                fbh[f] = *(const bf16x8*)&Bs0[ib];
                fbl[f] = *(const bf16x8*)&Bs1[ib];
            }
            #pragma unroll
            for (int i = 0; i < 2; ++i)
                #pragma unroll
                for (int j = 0; j < 2; ++j) {
                    acc[i][j] = __builtin_amdgcn_mfma_f32_16x16x32_bf16(fah[i], fbh[j], acc[i][j], 0, 0, 0);
                    acc[i][j] = __builtin_amdgcn_mfma_f32_16x16x32_bf16(fah[i], fbl[j], acc[i][j], 0, 0, 0);
                    acc[i][j] = __builtin_amdgcn_mfma_f32_16x16x32_bf16(fal[i], fbh[j], acc[i][j], 0, 0, 0);
                }
        }
    }
    __syncthreads();
    float* LF = (float*)SM;               // [64][64] f32
    #pragma unroll
    for (int i = 0; i < 2; ++i) {
        int row0 = wm + (i << 4) + ((lane >> 4) << 2);
        #pragma unroll
        for (int j = 0; j < 2; ++j) {
            int col = wn + (j << 4) + (lane & 15);
            #pragma unroll
            for (int r = 0; r < 4; ++r)
                LF[(row0 + r) * 64 + col] = acc[i][j][r];
        }
    }
    __syncthreads();
    float* Pp = P + (size_t)blockIdx.z * ((size_t)M * Nplane);
    #pragma unroll
    for (int it = 0; it < 4; ++it) {
        int idx = tid + (it << 8);
        int row = idx >> 4, c4 = (idx & 15) << 2;
        if (bm + row < M && bn + c4 < Nplane)
            *(float4*)(Pp + (size_t)(bm + row) * Nplane + bn + c4) = *(const float4*)&LF[row * 64 + c4];
    }
}

// ============ dual small GEMM: tuT (B1=hu) and tnT (B2=hn), shared A (gW) ============
__global__ __launch_bounds__(256) __attribute__((amdgpu_waves_per_eu(4, 8)))
void gemm_ks_dual(
        const ushort* __restrict__ Ah, const ushort* __restrict__ Al, int lda,
        const ushort* __restrict__ B1h, const ushort* __restrict__ B1l,
        const ushort* __restrict__ B2h, const ushort* __restrict__ B2l,
        float* __restrict__ P1, float* __restrict__ P2, int K, int Kc) {
    __shared__ __align__(16) ushort SM[4 * 64 * 64];
    ushort* As0 = SM;
    ushort* As1 = SM + 4096;
    ushort* Bs0 = SM + 8192;
    ushort* Bs1 = SM + 12288;
    const int tid = threadIdx.x;
    const bool second = (blockIdx.x >= 32);
    const int bn = (second ? (blockIdx.x - 32) : blockIdx.x) << 6;
    const int bm = blockIdx.y << 6;
    const ushort* Bh = second ? B2h : B1h;
    const ushort* Bl = second ? B2l : B1l;
    const int Nb = second ? NN : UU;
    const int Nplane = second ? N4P : UU;
    float* P = second ? P2 : P1;
    const int M = 256, ldb = 256;
    const int lane = tid & 63;
    const int wv = tid >> 6;
    const int wm = (wv >> 1) << 5, wn = (wv & 1) << 5;
    const int kb = blockIdx.z * Kc;
    int ke = kb + Kc; if (ke > K) ke = K;
    const int rb = wv << 4;
    f32x4 acc[2][2] = {};
    for (int k0 = kb; k0 < ke; k0 += 64) {
        __syncthreads();
        #pragma unroll
        for (int t = 0; t < 2; ++t) {
            int rb2 = rb + (t << 3);
            int row = rb2 + (lane >> 3);
            int kksrc = (((lane & 7) ^ (row & 7)) << 3);
            int ga = bm + row;
            int gb = bn + row; gb = (gb < Nb) ? gb : (Nb - 1);
            size_t goa = (size_t)ga * lda + k0 + kksrc;
            size_t gob = (size_t)gb * ldb + k0 + kksrc;
            GLL16(Ah + goa, &As0[rb2 << 6]);
            GLL16(Al + goa, &As1[rb2 << 6]);
            GLL16(Bh + gob, &Bs0[rb2 << 6]);
            GLL16(Bl + gob, &Bs1[rb2 << 6]);
        }
        __syncthreads();
        #pragma unroll
        for (int ks = 0; ks < 2; ++ks) {
            int kbq = (ks << 5) + ((lane >> 4) << 3);
            bf16x8 fah[2], fal[2], fbh[2], fbl[2];
            #pragma unroll
            for (int f = 0; f < 2; ++f) {
                int rr = wm + (f << 4) + (lane & 15);
                int ia = ((rr << 6) + kbq) ^ ((rr & 7) << 3);
                fah[f] = *(const bf16x8*)&As0[ia];
                fal[f] = *(const bf16x8*)&As1[ia];
                int cc = wn + (f << 4) + (lane & 15);
                int ib = ((cc << 6) + kbq) ^ ((cc & 7) << 3);
                fbh[f] = *(const bf16x8*)&Bs0[ib];
                fbl[f] = *(const bf16x8*)&Bs1[ib];
            }
            #pragma unroll
            for (int i = 0; i < 2; ++i)
                #pragma unroll
                for (int j = 0; j < 2; ++j) {
                    acc[i][j] = __builtin_amdgcn_mfma_f32_16x16x32_bf16(fah[i], fbh[j], acc[i][j], 0, 0, 0);
                    acc[i][j] = __builtin_amdgcn_mfma_f32_16x16x32_bf16(fah[i], fbl[j], acc[i][j], 0, 0, 0);
                    acc[i][j] = __builtin_amdgcn_mfma_f32_16x16x32_bf16(fal[i], fbh[j], acc[i][j], 0, 0, 0);
                }
        }
    }
    __syncthreads();
    float* LF = (float*)SM;
    #pragma unroll
    for (int i = 0; i < 2; ++i) {
        int row0 = wm + (i << 4) + ((lane >> 4) << 2);
        #pragma unroll
        for (int j = 0; j < 2; ++j) {
            int col = wn + (j << 4) + (lane & 15);
            #pragma unroll
            for (int r = 0; r < 4; ++r)
                LF[(row0 + r) * 64 + col] = acc[i][j][r];
        }
    }
    __syncthreads();
    float* Pp = P + (size_t)blockIdx.z * ((size_t)M * Nplane);
    #pragma unroll
    for (int it = 0; it < 4; ++it) {
        int idx = tid + (it << 8);
        int row = idx >> 4, c4 = (idx & 15) << 2;
        if (bn + c4 < Nplane)
            *(float4*)(Pp + (size_t)(bm + row) * Nplane + bn + c4) = *(const float4*)&LF[row * 64 + c4];
    }
}

// ---- dual reduce: tuT from P1 (zg=2), tnT from P2 (zg=2), both -> bf16 pairs ----
__global__ __launch_bounds__(256) void reduce_dual(
        const float* __restrict__ P1, const float* __restrict__ P2,
        ushort* __restrict__ T1h, ushort* __restrict__ T1l,
        ushort* __restrict__ T2h, ushort* __restrict__ T2l) {
    const int tot1 = 256 * (UU >> 2);
    const int tot2 = 256 * (N4P >> 2);
    int t = blockIdx.x * 256 + threadIdx.x;
    const float* P; int m, n, Npl, ldo; ushort *Ch, *Cl;
    if (t < tot1) {
        m = t / (UU >> 2); n = (t - m * (UU >> 2)) << 2;
        P = P1; Npl = UU; ldo = UU; Ch = T1h; Cl = T1l;
    } else {
        t -= tot1;
        if (t >= tot2) return;
        m = t / (N4P >> 2); n = (t - m * (N4P >> 2)) << 2;
        P = P2; Npl = N4P; ldo = KP; Ch = T2h; Cl = T2l;
    }
    size_t pstr = (size_t)256 * Npl;
    const float* base = P + (size_t)m * Npl + n;
    float4 a = *(const float4*)base;
    float4 b = *(const float4*)(base + pstr);
    a.x += b.x; a.y += b.y; a.z += b.z; a.w += b.w;
    ushort4 hv, lv;
    bfsplit(a.x, hv.x, lv.x); bfsplit(a.y, hv.y, lv.y);
    bfsplit(a.z, hv.z, lv.z); bfsplit(a.w, hv.w, lv.w);
    size_t co = (size_t)m * ldo + n;
    *(ushort4*)(Ch + co) = hv;
    *(ushort4*)(Cl + co) = lv;
}

// ---- reduce planes + epilogue: C = act(sum_z P[z] + bias + res) ----
template<int ACT, int BIAS, int RES, int OUTK>
__global__ __launch_bounds__(256) void reduce_ks(
        const float* __restrict__ P, int zg,
        const float* __restrict__ bias,
        const ushort* __restrict__ Rh, const ushort* __restrict__ Rl,
        float* __restrict__ Cf, ushort* __restrict__ Ch, ushort* __restrict__ Cl,
        int M, int N4, int ldo) {
    int t = blockIdx.x * 256 + threadIdx.x;
    int n4w = N4 >> 2;
    int tot = M * n4w;
    if (t >= tot) return;
    int m = t / n4w;
    int n = (t - m * n4w) << 2;
    size_t pstr = (size_t)M * N4;
    const float* base = P + (size_t)m * N4 + n;
    float4 a = *(const float4*)base;
    for (int z = 1; z < zg; ++z) {
        float4 b = *(const float4*)(base + (size_t)z * pstr);
        a.x += b.x; a.y += b.y; a.z += b.z; a.w += b.w;
    }
    if (BIAS == 1) {
        float4 bv = *(const float4*)(bias + n);
        a.x += bv.x; a.y += bv.y; a.z += bv.z; a.w += bv.w;
    }
    if (BIAS == 2) {
        float s = bias[m];
        a.x += s; a.y += s; a.z += s; a.w += s;
    }
    if (RES) {
        size_t ro = (size_t)m * ldo + n;
        ushort4 rh = *(const ushort4*)(Rh + ro);
        ushort4 rl = *(const ushort4*)(Rl + ro);
        a.x += bf2f(rh.x) + bf2f(rl.x); a.y += bf2f(rh.y) + bf2f(rl.y);
        a.z += bf2f(rh.z) + bf2f(rl.z); a.w += bf2f(rh.w) + bf2f(rl.w);
    }
    if (ACT == 1) {
        a.x = fmaxf(a.x, 0.f); a.y = fmaxf(a.y, 0.f);
        a.z = fmaxf(a.z, 0.f); a.w = fmaxf(a.w, 0.f);
    }
    if (ACT == 2) {
        a.x = tanhf(a.x); a.y = tanhf(a.y); a.z = tanhf(a.z); a.w = tanhf(a.w);
    }
    size_t co = (size_t)m * ldo + n;
    if (OUTK == 0) {
        *(float4*)(Cf + co) = a;
    } else {
        ushort4 hv, lv;
        bfsplit(a.x, hv.x, lv.x); bfsplit(a.y, hv.y, lv.y);
        bfsplit(a.z, hv.z, lv.z); bfsplit(a.w, hv.w, lv.w);
        *(ushort4*)(Ch + co) = hv;
        *(ushort4*)(Cl + co) = lv;
    }
}

static inline int rgrid(int M, int N4) { return (M * (N4 >> 2) + 255) / 256; }

extern "C" void kernel_launch(void* const* d_in, const int* in_sizes, int n_in,
                              void* d_out, int out_size, void* d_ws, size_t ws_size,
                              hipStream_t stream) {
    const float* dsf = (const float*)d_in[0];
    const float* unl = (const float*)d_in[1];
    const float* S   = (const float*)d_in[2];
    const float* Wb  = (const float*)d_in[3];
    const float* bb  = (const float*)d_in[4];
    const float* gcW[3] = {(const float*)d_in[5], (const float*)d_in[7], (const float*)d_in[9]};
    const float* gcb[3] = {(const float*)d_in[6], (const float*)d_in[8], (const float*)d_in[10]};
    const float* W1 = (const float*)d_in[11];
    const float* b1 = (const float*)d_in[12];
    const float* W2 = (const float*)d_in[13];
    const float* b2 = (const float*)d_in[14];
    float* out = (float*)d_out;

    // -------- workspace carve --------
    char* p = (char*)d_ws;
    ushort* Shm = (ushort*)p; p += (size_t)NN * UU * 2;                // 16.4 MB fp16 S
    ushort* STh = (ushort*)p; p += (size_t)UU * KP * 2;                // 16.5 MB fp16 S^T
    float* P    = (float*)p;  p += (size_t)16 * UU * 256 * 4;          // 33.6 MB planes (max z=16 UU / z=8 NN)
    ushort* fh = (ushort*)p; ushort* fl = fh + (size_t)NN * 256; p += (size_t)NN * 256 * 4;
    ushort* xh = (ushort*)p; ushort* xl = xh + (size_t)NN * 256; p += (size_t)NN * 256 * 4;
    ushort* xTh = (ushort*)p; ushort* xTl = xTh + (size_t)256 * KP; p += (size_t)256 * KP * 4;
    ushort* huh = (ushort*)p; ushort* hul = huh + (size_t)UU * 256; p += (size_t)UU * 256 * 4;
    ushort* tuTh = (ushort*)p; ushort* tuTl = tuTh + (size_t)256 * UU; p += (size_t)256 * UU * 4;
    ushort* tnTh = (ushort*)p; ushort* tnTl = tnTh + (size_t)256 * KP; p += (size_t)256 * KP * 4;
    float* u_ext = (float*)p; p += KP * 4;
    float* v     = (float*)p; p += UU * 4;
    ushort* WbTh = (ushort*)p; ushort* WbTl = WbTh + 256 * 256; p += 256 * 256 * 4;
    ushort* gWh[3]; ushort* gWl[3];
    for (int l = 0; l < 3; ++l) { gWh[l] = (ushort*)p; gWl[l] = gWh[l] + 256 * 256; p += 256 * 256 * 4; }
    ushort* W1Th = (ushort*)p; ushort* W1Tl = W1Th + 512 * 256; p += 512 * 256 * 4;
    ushort* W2Th = (ushort*)p; ushort* W2Tl = W2Th + 256 * 512; p += 256 * 512 * 4;
    // dual-GEMM plane regions inside P
    float* P1 = P;
    float* P2 = P + (size_t)2 * 256 * UU;
    // h1 pair aliases x + start of xT region (both dead by head time)
    ushort* h1h = xh; ushort* h1l = h1h + (size_t)UU * 512;
    (void)ws_size;

    // -------- prep --------
    concat_bf<<<dim3(1004), dim3(256), 0, stream>>>(dsf, unl, fh, fl, u_ext, v);
    convW_all<<<dim3(16, 16, 6), dim3(32, 8), 0, stream>>>(
        Wb, gcW[0], gcW[1], gcW[2], W1, W2,
        WbTh, WbTl, gWh[0], gWl[0], gWh[1], gWl[1], gWh[2], gWl[2],
        W1Th, W1Tl, W2Th, W2Tl);
    conv_both<<<dim3(64, 126), dim3(32, 8), 0, stream>>>(S, Shm, STh);

    // x = relu(feats @ Wb + bb)  [NN][256]
    gemm_ks<<<dim3(4, 63, 2), 256, 0, stream>>>(
        fh, fl, 256, WbTh, WbTl, 256, 256, P, NN, 256, 256, 128);
    reduce_ks<1,1,0,1><<<rgrid(NN,256), 256, 0, stream>>>(
        P, 2, bb, nullptr, nullptr, nullptr, xh, xl, NN, 256, 256);
    // xT = x^T  [256][KP]
    gemm_ks<<<dim3(63, 4, 2), 256, 0, stream>>>(
        WbTh, WbTl, 256, fh, fl, 256, NN, P, 256, N4P, 256, 128);
    reduce_ks<1,2,0,1><<<rgrid(256,N4P), 256, 0, stream>>>(
        P, 2, bb, nullptr, nullptr, nullptr, xTh, xTl, 256, N4P, KP);

    // -------- Sinkhorn (fp16 S, f32 math): 40 small launches --------
    // (R10: grid.sync ~25us/sync; R13: per-block __threadfence ~L2-writeback — both lose
    //  to graph-replayed launches. Keep the 40-launch loop.)
    for (int it = 0; it < 20; ++it) {
        lse4h<<<dim3((NN + 3) / 4), dim3(256), 0, stream>>>(Shm, UU, v, u_ext, UU, NN);
        lse4h<<<dim3(UU / 4),       dim3(256), 0, stream>>>(STh, KP, u_ext, v, NN, UU);
    }

    // -------- G1: hu0 = A^T @ x  [UU][256]  (z=16 -> 512 blocks = 2/CU) --------
    gemm_bigN<<<dim3(32, 16), 512, 0, stream>>>(
        STh, v, u_ext, KP, xTh, xTl, KP, P, UU, KP, 256);
    reduce_ks<0,0,0,1><<<rgrid(UU,256), 256, 0, stream>>>(
        P, 16, nullptr, nullptr, nullptr, nullptr, huh, hul, UU, 256, 256);

    // -------- 3 GCN layers --------
    const int dual_grid = (256 * (UU >> 2) + 256 * (N4P >> 2) + 255) / 256;
    for (int l = 0; l < 3; ++l) {
        const ushort* hnh = (l == 0) ? xh : fh;
        const ushort* hnl = (l == 0) ? xl : fl;
        if (l < 2) {
            gemm_ks_dual<<<dim3(95, 4, 2), 256, 0, stream>>>(
                gWh[l], gWl[l], 256, huh, hul, hnh, hnl, P1, P2, 256, 128);
            reduce_dual<<<dim3(dual_grid), 256, 0, stream>>>(
                P1, P2, tuTh, tuTl, tnTh, tnTl);
        } else {
            gemm_ks<<<dim3(63, 4, 2), 256, 0, stream>>>(
                gWh[l], gWl[l], 256, hnh, hnl, 256, NN, P, 256, N4P, 256, 128);
            reduce_ks<0,0,0,1><<<rgrid(256,N4P), 256, 0, stream>>>(
                P, 2, nullptr, nullptr, nullptr, nullptr, tnTh, tnTl, 256, N4P, KP);
        }
        if (l < 2) {
            // hn_next = tanh(A @ t_u + b + hn), z=8 -> 504 blocks ~ 2/CU
            gemm_bigN<<<dim3(63, 8), 512, 0, stream>>>(
                Shm, u_ext, v, UU, tuTh, tuTl, UU, P, NN, UU, 256);
            reduce_ks<2,1,1,1><<<rgrid(NN,256), 256, 0, stream>>>(
                P, 8, gcb[l], hnh, hnl, nullptr, fh, fl, NN, 256, 256);
        }
        // hu_next = tanh(A^T @ t_n + b + hu), z=16
        gemm_bigN<<<dim3(32, 16), 512, 0, stream>>>(
            STh, v, u_ext, KP, tnTh, tnTl, KP, P, UU, KP, 256);
        reduce_ks<2,1,1,1><<<rgrid(UU,256), 256, 0, stream>>>(
            P, 16, gcb[l], huh, hul, nullptr, huh, hul, UU, 256, 256);
    }

    // -------- head --------
    gemm_ks<<<dim3(8, 32, 2), 256, 0, stream>>>(
        huh, hul, 256, W1Th, W1Tl, 256, 512, P, UU, 512, 256, 128);
    reduce_ks<1,1,0,1><<<rgrid(UU,512), 256, 0, stream>>>(
        P, 2, b1, nullptr, nullptr, nullptr, h1h, h1l, UU, 512, 512);
    gemm_ks<<<dim3(4, 32, 4), 256, 0, stream>>>(
        h1h, h1l, 512, W2Th, W2Tl, 512, 256, P, UU, 256, 512, 128);
    reduce_ks<0,1,0,0><<<rgrid(UU,256), 256, 0, stream>>>(
        P, 4, b2, nullptr, nullptr, out, nullptr, nullptr, UU, 256, 256);
}